// Round 8
// baseline (890.082 us; speedup 1.0000x reference)
//
#include <hip/hip_runtime.h>
#include <cstdint>

#define NN 50000
#define NE 800000
#define NG 64
#define HD 128
#define FT 64
#define NLAYERS 3
#define MB 32
#define NBLK 1563   // ceil(NN/MB)

// ---------- graph boundaries (batch is sorted contiguous runs) ----------
__global__ void k_gbounds(const int* __restrict__ batch, int* __restrict__ gstart){
    int i = blockIdx.x*blockDim.x + threadIdx.x;
    if (i >= NN) return;
    int g = batch[i];
    if (i == 0){ for (int q = 0; q <= g; ++q) gstart[q] = 0; }
    else { int gp = batch[i-1]; for (int q = gp+1; q <= g; ++q) gstart[q] = i; }
    if (i == NN-1){ for (int q = g+1; q <= NG; ++q) gstart[q] = NN; }
}

// ---------- block-wide min/max reduce helper (256 threads = 4 waves) ----------
__device__ __forceinline__ void block_minmax(float lmn, float lmx, float* red,
                                             float& omn, float& omx){
    #pragma unroll
    for (int off = 32; off > 0; off >>= 1){
        lmn = fminf(lmn, __shfl_xor(lmn, off));
        lmx = fmaxf(lmx, __shfl_xor(lmx, off));
    }
    int wave = threadIdx.x >> 6;
    if ((threadIdx.x & 63) == 0){ red[wave] = lmn; red[4+wave] = lmx; }
    __syncthreads();
    omn = fminf(fminf(red[0], red[1]), fminf(red[2], red[3]));
    omx = fmaxf(fmaxf(red[4], red[5]), fmaxf(red[6], red[7]));
    __syncthreads();
}

// ---------- per-graph normalize (initial importance only) ----------
__global__ __launch_bounds__(256) void k_norm_graph(
    const float* __restrict__ va, const int* __restrict__ gstart,
    float* __restrict__ out)
{
    __shared__ float sv[1024];
    __shared__ float red[8];
    int g = blockIdx.x;
    int s = gstart[g], n = gstart[g+1] - s;
    int tid = threadIdx.x;
    float lmn = 3.4e38f, lmx = -3.4e38f;
    for (int i = tid; i < n; i += 256){
        float v = va[s+i];
        sv[i] = v;
        lmn = fminf(lmn, v); lmx = fmaxf(lmx, v);
    }
    float lo, hi;
    block_minmax(lmn, lmx, red, lo, hi);
    float inv = 1.f/(hi - lo + 1e-8f);
    for (int i = tid; i < n; i += 256) out[s+i] = (sv[i] - lo)*inv;
}

// Fold imp_proj into init_W: W0 is (FT+1) x HD, b0 = init_b + pb @ init_W[FT:]
__global__ void k_fold_init(const float* __restrict__ pW, const float* __restrict__ pb,
                            const float* __restrict__ iW, const float* __restrict__ ib,
                            float* __restrict__ W0, float* __restrict__ b0){
    int j = threadIdx.x;
    for (int k = 0; k < FT; ++k) W0[k*HD + j] = iW[k*HD + j];
    float w2 = 0.f, b2 = 0.f;
    for (int k = 0; k < HD; ++k){
        float w = iW[(FT + k)*HD + j];
        w2 += pW[k]*w;
        b2 += pb[k]*w;
    }
    W0[FT*HD + j] = w2;
    b0[j] = ib[j] + b2;
}

// Wf(256x128) = [uW_top ; msg_W @ uW_bot], bcv = msg_b @ uW_bot.
// grid (257, NLAYERS) x 128.
__global__ void k_fold_layer(const float* __restrict__ msgW, const float* __restrict__ updW,
                             const float* __restrict__ msgb,
                             float* __restrict__ WfA, float* __restrict__ bcvA){
    int l = blockIdx.y;
    const float* mW  = msgW + (size_t)l*HD*HD;
    const float* uW  = updW + (size_t)l*2*HD*HD;
    const float* mb  = msgb + (size_t)l*HD;
    float* Wf  = WfA  + (size_t)l*2*HD*HD;
    float* bcv = bcvA + (size_t)l*HD;
    int j = threadIdx.x;
    int r = blockIdx.x;
    if (r < HD){
        Wf[(size_t)r*HD + j] = uW[(size_t)r*HD + j];
    } else if (r < 2*HD){
        int rr = r - HD;
        const float* uWbot = uW + (size_t)HD*HD;
        float acc = 0.f;
        for (int k = 0; k < HD; ++k)
            acc = fmaf(mW[(size_t)rr*HD + k], uWbot[(size_t)k*HD + j], acc);
        Wf[(size_t)r*HD + j] = acc;
    } else {
        const float* uWbot = uW + (size_t)HD*HD;
        float acc = 0.f;
        for (int k = 0; k < HD; ++k)
            acc = fmaf(mb[k], uWbot[(size_t)k*HD + j], acc);
        bcv[j] = acc;
    }
}

// ---------- init GEMM: h = x @ W0[0:64] + imp*W0[64] + b0 ----------
__global__ __launch_bounds__(256) void k_init(
    const float* __restrict__ x, const float* __restrict__ imp,
    const float* __restrict__ W0, const float* __restrict__ b0v,
    float* __restrict__ h)
{
    __shared__ float lds[MB][FT];
    __shared__ float scs[MB];
    int base = blockIdx.x*MB, tid = threadIdx.x;
    #pragma unroll
    for (int i = 0; i < 2; ++i){
        int fidx = i*256 + tid;
        int t = fidx >> 4, c = fidx & 15;
        float4 v = {0.f,0.f,0.f,0.f};
        if (base + t < NN) v = *(const float4*)&x[(size_t)(base+t)*FT + c*4];
        *(float4*)&lds[t][c*4] = v;
    }
    if (tid < MB) scs[tid] = (base+tid < NN) ? imp[base+tid] : 0.f;
    __syncthreads();

    const int cg = tid & 31, rg = tid >> 5;
    const int c0 = cg*4, r0 = rg*4;
    const float4 wl4 = *(const float4*)&W0[(size_t)FT*HD + c0];
    const float4 b4  = *(const float4*)&b0v[c0];
    float acc[4][4];
    #pragma unroll
    for (int r = 0; r < 4; ++r){
        float s = scs[r0+r];
        acc[r][0] = fmaf(s, wl4.x, b4.x); acc[r][1] = fmaf(s, wl4.y, b4.y);
        acc[r][2] = fmaf(s, wl4.z, b4.z); acc[r][3] = fmaf(s, wl4.w, b4.w);
    }
    #pragma unroll 4
    for (int k4 = 0; k4 < 16; ++k4){
        const float4 w0 = *(const float4*)&W0[(size_t)(k4*4+0)*HD + c0];
        const float4 w1 = *(const float4*)&W0[(size_t)(k4*4+1)*HD + c0];
        const float4 w2 = *(const float4*)&W0[(size_t)(k4*4+2)*HD + c0];
        const float4 w3 = *(const float4*)&W0[(size_t)(k4*4+3)*HD + c0];
        #pragma unroll
        for (int r = 0; r < 4; ++r){
            const float4 a = *(const float4*)&lds[r0+r][k4*4];
            acc[r][0]=fmaf(a.x,w0.x,fmaf(a.y,w1.x,fmaf(a.z,w2.x,fmaf(a.w,w3.x,acc[r][0]))));
            acc[r][1]=fmaf(a.x,w0.y,fmaf(a.y,w1.y,fmaf(a.z,w2.y,fmaf(a.w,w3.y,acc[r][1]))));
            acc[r][2]=fmaf(a.x,w0.z,fmaf(a.y,w1.z,fmaf(a.z,w2.z,fmaf(a.w,w3.z,acc[r][2]))));
            acc[r][3]=fmaf(a.x,w0.w,fmaf(a.y,w1.w,fmaf(a.z,w2.w,fmaf(a.w,w3.w,acc[r][3]))));
        }
    }
    #pragma unroll
    for (int r = 0; r < 4; ++r)
        if (base + r0 + r < NN)
            *(float4*)&h[(size_t)(base+r0+r)*HD + c0] =
                make_float4(acc[r][0], acc[r][1], acc[r][2], acc[r][3]);
}

// FMA micro-step: 8 k-rows (two lds float4s a,b; weights w0..w7) into acc[r][*]
#define FMA8(r, a, b, W0_,W1_,W2_,W3_,W4_,W5_,W6_,W7_, A) \
    A[r][0]=fmaf((b).x,W4_.x,fmaf((b).y,W5_.x,fmaf((b).z,W6_.x,fmaf((b).w,W7_.x, \
            fmaf((a).x,W0_.x,fmaf((a).y,W1_.x,fmaf((a).z,W2_.x,fmaf((a).w,W3_.x,A[r][0])))))))); \
    A[r][1]=fmaf((b).x,W4_.y,fmaf((b).y,W5_.y,fmaf((b).z,W6_.y,fmaf((b).w,W7_.y, \
            fmaf((a).x,W0_.y,fmaf((a).y,W1_.y,fmaf((a).z,W2_.y,fmaf((a).w,W3_.y,A[r][1])))))))); \
    A[r][2]=fmaf((b).x,W4_.z,fmaf((b).y,W5_.z,fmaf((b).z,W6_.z,fmaf((b).w,W7_.z, \
            fmaf((a).x,W0_.z,fmaf((a).y,W1_.z,fmaf((a).z,W2_.z,fmaf((a).w,W3_.z,A[r][2])))))))); \
    A[r][3]=fmaf((b).x,W4_.w,fmaf((b).y,W5_.w,fmaf((b).z,W6_.w,fmaf((b).w,W7_.w, \
            fmaf((a).x,W0_.w,fmaf((a).y,W1_.w,fmaf((a).z,W2_.w,fmaf((a).w,W3_.w,A[r][3]))))))));

// ---------- per-layer mega kernel (LDS-staged weight tiles) ----------
// LDS: act 32KB + wtile 16KB ~= 48.5KB -> 3 blocks/CU.
__global__ __launch_bounds__(256, 3) void k_layer(
    const float* __restrict__ h, const float* __restrict__ aggr,
    const float* __restrict__ imp, const int* __restrict__ deg,
    const float* __restrict__ Wf, const float* __restrict__ bcv,
    const float* __restrict__ ub,
    const float* __restrict__ gW, const float* __restrict__ gb,
    const float* __restrict__ prW, const float* __restrict__ prb,
    float* __restrict__ outbuf, float* __restrict__ ta)
{
    __shared__ float lds[MB][256];   // cols 0..127: h ; 128..255: aggr, then conv
    __shared__ float wlds[32][HD];   // weight K-tile (32 rows x 128 cols)
    __shared__ float scs[MB];
    __shared__ float dgs[MB];
    __shared__ float red[8][4];
    const int base = blockIdx.x*MB, tid = threadIdx.x;
    float4* wl4 = (float4*)wlds;

    #pragma unroll
    for (int i = 0; i < 8; ++i){
        int fidx = i*256 + tid;
        int t = fidx >> 6, c = fidx & 63;
        float4 v = {0.f,0.f,0.f,0.f};
        if (base + t < NN){
            const float* srcp = (c < 32) ? &h[(size_t)(base+t)*HD + c*4]
                                         : &aggr[(size_t)(base+t)*HD + (c-32)*4];
            v = *(const float4*)srcp;
        }
        *(float4*)&lds[t][c*4] = v;
    }
    if (tid < MB) scs[tid] = (base+tid < NN) ? imp[base+tid] : 0.f;
    else if (tid < 2*MB){
        int t = tid - MB;
        dgs[t] = (base+t < NN) ? (float)deg[base+t] : 0.f;
    }

    const int cg = tid & 31, rg = tid >> 5;
    const int c0 = cg*4, r0 = rg*4;

    // prefetch conv weight tile 0 (issues before staging barrier)
    const float4* wv4 = (const float4*)Wf;   // 256 rows x 32 float4
    float4 wr0 = wv4[tid], wr1 = wv4[256+tid], wr2 = wv4[512+tid], wr3 = wv4[768+tid];
    __syncthreads();

    // ---- conv = [h|aggr] @ Wf + deg*bc + ub  (8 tiles of 32 K-rows)
    const float4 bc4 = *(const float4*)&bcv[c0];
    const float4 ub4 = *(const float4*)&ub[c0];
    float acc[4][4];
    #pragma unroll
    for (int r = 0; r < 4; ++r){
        float d = dgs[r0+r];
        acc[r][0] = fmaf(d, bc4.x, ub4.x); acc[r][1] = fmaf(d, bc4.y, ub4.y);
        acc[r][2] = fmaf(d, bc4.z, ub4.z); acc[r][3] = fmaf(d, bc4.w, ub4.w);
    }
    for (int t = 0; t < 8; ++t){
        __syncthreads();                   // prev tile's wlds reads done
        wl4[tid] = wr0; wl4[256+tid] = wr1; wl4[512+tid] = wr2; wl4[768+tid] = wr3;
        __syncthreads();                   // tile written
        if (t < 7){
            const float4* np = wv4 + (size_t)(t+1)*1024;
            wr0 = np[tid]; wr1 = np[256+tid]; wr2 = np[512+tid]; wr3 = np[768+tid];
        }
        const int kb0 = t*32;
        #pragma unroll
        for (int kk = 0; kk < 32; kk += 8){
            const float4 w0 = *(const float4*)&wlds[kk+0][c0];
            const float4 w1 = *(const float4*)&wlds[kk+1][c0];
            const float4 w2 = *(const float4*)&wlds[kk+2][c0];
            const float4 w3 = *(const float4*)&wlds[kk+3][c0];
            const float4 w4 = *(const float4*)&wlds[kk+4][c0];
            const float4 w5 = *(const float4*)&wlds[kk+5][c0];
            const float4 w6 = *(const float4*)&wlds[kk+6][c0];
            const float4 w7 = *(const float4*)&wlds[kk+7][c0];
            #pragma unroll
            for (int r = 0; r < 4; ++r){
                const float4 a = *(const float4*)&lds[r0+r][kb0+kk];
                const float4 b = *(const float4*)&lds[r0+r][kb0+kk+4];
                FMA8(r, a, b, w0,w1,w2,w3,w4,w5,w6,w7, acc)
            }
        }
    }
    __syncthreads();   // all conv-GEMM reads (aggr cols + wlds) done

    // stash conv into cols 128..255; prefetch gate tile 0
    #pragma unroll
    for (int r = 0; r < 4; ++r)
        *(float4*)&lds[r0+r][HD + c0] = make_float4(acc[r][0],acc[r][1],acc[r][2],acc[r][3]);
    const float4* gv4 = (const float4*)gW;   // 129 rows x 32 float4
    wr0 = gv4[tid]; wr1 = gv4[256+tid]; wr2 = gv4[512+tid]; wr3 = gv4[768+tid];

    // ---- gate z = conv@gW_top + imp*gW[128] + gb  (4 tiles of 32 K-rows)
    const float4 gwl = gv4[(size_t)HD*32 + cg];
    const float4 gb4 = *(const float4*)&gb[c0];
    float z[4][4];
    #pragma unroll
    for (int r = 0; r < 4; ++r){
        float s = scs[r0+r];
        z[r][0] = fmaf(s, gwl.x, gb4.x); z[r][1] = fmaf(s, gwl.y, gb4.y);
        z[r][2] = fmaf(s, gwl.z, gb4.z); z[r][3] = fmaf(s, gwl.w, gb4.w);
    }
    for (int t = 0; t < 4; ++t){
        __syncthreads();                   // conv writes visible / prev reads done
        wl4[tid] = wr0; wl4[256+tid] = wr1; wl4[512+tid] = wr2; wl4[768+tid] = wr3;
        __syncthreads();
        if (t < 3){
            const float4* np = gv4 + (size_t)(t+1)*1024;
            wr0 = np[tid]; wr1 = np[256+tid]; wr2 = np[512+tid]; wr3 = np[768+tid];
        }
        const int kb0 = t*32;
        #pragma unroll
        for (int kk = 0; kk < 32; kk += 8){
            const float4 w0 = *(const float4*)&wlds[kk+0][c0];
            const float4 w1 = *(const float4*)&wlds[kk+1][c0];
            const float4 w2 = *(const float4*)&wlds[kk+2][c0];
            const float4 w3 = *(const float4*)&wlds[kk+3][c0];
            const float4 w4 = *(const float4*)&wlds[kk+4][c0];
            const float4 w5 = *(const float4*)&wlds[kk+5][c0];
            const float4 w6 = *(const float4*)&wlds[kk+6][c0];
            const float4 w7 = *(const float4*)&wlds[kk+7][c0];
            #pragma unroll
            for (int r = 0; r < 4; ++r){
                const float4 a = *(const float4*)&lds[r0+r][HD + kb0+kk];
                const float4 b = *(const float4*)&lds[r0+r][HD + kb0+kk+4];
                FMA8(r, a, b, w0,w1,w2,w3,w4,w5,w6,w7, z)
            }
        }
    }

    // epilogue: gate mix, store out, prop partials (conv still in acc regs)
    const float4 pr4 = *(const float4*)&prW[c0];
    float psum[4];
    #pragma unroll
    for (int r = 0; r < 4; ++r){
        const float4 hv = *(const float4*)&lds[r0+r][c0];
        float g0 = 1.f/(1.f + expf(-z[r][0]));
        float g1 = 1.f/(1.f + expf(-z[r][1]));
        float g2 = 1.f/(1.f + expf(-z[r][2]));
        float g3 = 1.f/(1.f + expf(-z[r][3]));
        float o0 = g0*acc[r][0] + (1.f-g0)*hv.x;
        float o1 = g1*acc[r][1] + (1.f-g1)*hv.y;
        float o2 = g2*acc[r][2] + (1.f-g2)*hv.z;
        float o3 = g3*acc[r][3] + (1.f-g3)*hv.w;
        if (base + r0 + r < NN)
            *(float4*)&outbuf[(size_t)(base+r0+r)*HD + c0] = make_float4(o0,o1,o2,o3);
        psum[r] = o0*pr4.x + o1*pr4.y + o2*pr4.z + o3*pr4.w;
    }
    #pragma unroll
    for (int r = 0; r < 4; ++r){
        float v = psum[r];
        #pragma unroll
        for (int off = 16; off > 0; off >>= 1) v += __shfl_xor(v, off);
        if (cg == 0) red[rg][r] = v;
    }
    __syncthreads();
    if (tid < MB && base + tid < NN)
        ta[base+tid] = 0.9f*scs[tid] + 0.1f*(red[tid>>2][tid&3] + prb[0]);
}

// ---------- CSR build (by dst) ----------
__global__ void k_deg(const int* __restrict__ dst, int* deg){
    int e = blockIdx.x*blockDim.x + threadIdx.x;
    if (e < NE) atomicAdd(&deg[dst[e]], 1);
}

__global__ __launch_bounds__(1024) void k_scan(const int* __restrict__ deg,
                                               int* __restrict__ rowstart){
    __shared__ int wtot[16];
    __shared__ int woff[16];
    __shared__ int carry;
    int tid = threadIdx.x, lane = tid & 63, wv = tid >> 6;
    if (tid == 0) carry = 0;
    __syncthreads();
    for (int base = 0; base < NN; base += 1024){
        int i = base + tid;
        int v = (i < NN) ? deg[i] : 0;
        int x = v;
        #pragma unroll
        for (int off = 1; off < 64; off <<= 1){
            int y = __shfl_up(x, off);
            if (lane >= off) x += y;
        }
        if (lane == 63) wtot[wv] = x;
        __syncthreads();
        if (tid == 0){
            int a = carry;
            for (int w2 = 0; w2 < 16; ++w2){ woff[w2] = a; a += wtot[w2]; }
            carry = a;
        }
        __syncthreads();
        if (i < NN) rowstart[i] = woff[wv] + x - v;   // exclusive
    }
    __syncthreads();
    if (tid == 0) rowstart[NN] = carry;
}

__global__ void k_copy_int(const int* __restrict__ a, int* __restrict__ b, int n){
    int i = blockIdx.x*blockDim.x + threadIdx.x;
    if (i < n) b[i] = a[i];
}

__global__ void k_fill(const int* __restrict__ src, const int* __restrict__ dst,
                       int* cursor, int* __restrict__ csr){
    int e = blockIdx.x*blockDim.x + threadIdx.x;
    if (e < NE){
        int d = dst[e];
        int p = atomicAdd(&cursor[d], 1);
        csr[p] = src[e];
    }
}

// aggr[node] = sum over in-edges of h[src]; 32 lanes/node, 8-edge ILP
__global__ __launch_bounds__(256) void k_aggregate(
    const float* __restrict__ hm, const int* __restrict__ rowstart,
    const int* __restrict__ csr, float* __restrict__ aggr)
{
    int node = blockIdx.x*8 + (threadIdx.x >> 5);
    int lane = threadIdx.x & 31;
    float4 a0 = {0.f,0.f,0.f,0.f}, a1 = a0, a2 = a0, a3 = a0;
    float4 a4 = a0, a5 = a0, a6 = a0, a7 = a0;
    int e0 = rowstart[node], e1 = rowstart[node+1];
    int e = e0;
    for (; e + 7 < e1; e += 8){
        int s0 = csr[e],   s1 = csr[e+1], s2 = csr[e+2], s3 = csr[e+3];
        int s4 = csr[e+4], s5 = csr[e+5], s6 = csr[e+6], s7 = csr[e+7];
        const float4 v0 = *(const float4*)&hm[(size_t)s0*HD + lane*4];
        const float4 v1 = *(const float4*)&hm[(size_t)s1*HD + lane*4];
        const float4 v2 = *(const float4*)&hm[(size_t)s2*HD + lane*4];
        const float4 v3 = *(const float4*)&hm[(size_t)s3*HD + lane*4];
        const float4 v4 = *(const float4*)&hm[(size_t)s4*HD + lane*4];
        const float4 v5 = *(const float4*)&hm[(size_t)s5*HD + lane*4];
        const float4 v6 = *(const float4*)&hm[(size_t)s6*HD + lane*4];
        const float4 v7 = *(const float4*)&hm[(size_t)s7*HD + lane*4];
        a0.x += v0.x; a0.y += v0.y; a0.z += v0.z; a0.w += v0.w;
        a1.x += v1.x; a1.y += v1.y; a1.z += v1.z; a1.w += v1.w;
        a2.x += v2.x; a2.y += v2.y; a2.z += v2.z; a2.w += v2.w;
        a3.x += v3.x; a3.y += v3.y; a3.z += v3.z; a3.w += v3.w;
        a4.x += v4.x; a4.y += v4.y; a4.z += v4.z; a4.w += v4.w;
        a5.x += v5.x; a5.y += v5.y; a5.z += v5.z; a5.w += v5.w;
        a6.x += v6.x; a6.y += v6.y; a6.z += v6.z; a6.w += v6.w;
        a7.x += v7.x; a7.y += v7.y; a7.z += v7.z; a7.w += v7.w;
    }
    for (; e + 3 < e1; e += 4){
        int s0 = csr[e], s1 = csr[e+1], s2 = csr[e+2], s3 = csr[e+3];
        const float4 v0 = *(const float4*)&hm[(size_t)s0*HD + lane*4];
        const float4 v1 = *(const float4*)&hm[(size_t)s1*HD + lane*4];
        const float4 v2 = *(const float4*)&hm[(size_t)s2*HD + lane*4];
        const float4 v3 = *(const float4*)&hm[(size_t)s3*HD + lane*4];
        a0.x += v0.x; a0.y += v0.y; a0.z += v0.z; a0.w += v0.w;
        a1.x += v1.x; a1.y += v1.y; a1.z += v1.z; a1.w += v1.w;
        a2.x += v2.x; a2.y += v2.y; a2.z += v2.z; a2.w += v2.w;
        a3.x += v3.x; a3.y += v3.y; a3.z += v3.z; a3.w += v3.w;
    }
    for (; e < e1; ++e){
        int s0 = csr[e];
        const float4 v0 = *(const float4*)&hm[(size_t)s0*HD + lane*4];
        a0.x += v0.x; a0.y += v0.y; a0.z += v0.z; a0.w += v0.w;
    }
    a0.x += a1.x; a0.y += a1.y; a0.z += a1.z; a0.w += a1.w;
    a2.x += a3.x; a2.y += a3.y; a2.z += a3.z; a2.w += a3.w;
    a4.x += a5.x; a4.y += a5.y; a4.z += a5.z; a4.w += a5.w;
    a6.x += a7.x; a6.y += a7.y; a6.z += a7.z; a6.w += a7.w;
    a0.x += a2.x; a0.y += a2.y; a0.z += a2.z; a0.w += a2.w;
    a4.x += a6.x; a4.y += a6.y; a4.z += a6.z; a4.w += a6.w;
    a0.x += a4.x; a0.y += a4.y; a0.z += a4.z; a0.w += a4.w;
    *(float4*)&aggr[(size_t)node*HD + lane*4] = a0;
}

// ---------- fused graph-norm (4 col-slices per graph) + importance chain ----
__global__ __launch_bounds__(256) void k_gnorm(
    const float* __restrict__ v, const int* __restrict__ gstart,
    const float* __restrict__ nw, const float* __restrict__ nb,
    const float* __restrict__ na, float* __restrict__ hout,
    const float* __restrict__ tsrc, float* __restrict__ tdst)
{
    int g = blockIdx.x;
    int part = blockIdx.y;
    int s = gstart[g], n = gstart[g+1] - s;
    int tid = threadIdx.x;

    if (part == 4){
        __shared__ float sv[1024];
        __shared__ float red[8];
        float lmn = 3.4e38f, lmx = -3.4e38f;
        for (int i = tid; i < n; i += 256){
            float val = tsrc[s+i]; sv[i] = val;
            lmn = fminf(lmn, val); lmx = fmaxf(lmx, val);
        }
        float lo, hi;
        block_minmax(lmn, lmx, red, lo, hi);
        float inv = 1.f/(hi - lo + 1e-8f);
        lmn = 3.4e38f; lmx = -3.4e38f;
        for (int i = tid; i < n; i += 256){
            float t2 = (sv[i] - lo)*inv;
            if (t2 < 0.1f) t2 = 0.f;
            sv[i] = t2;
            lmn = fminf(lmn, t2); lmx = fmaxf(lmx, t2);
        }
        float lo2, hi2;
        block_minmax(lmn, lmx, red, lo2, hi2);
        float inv2 = 1.f/(hi2 - lo2 + 1e-8f);
        for (int i = tid; i < n; i += 256) tdst[s+i] = (sv[i] - lo2)*inv2;
        return;
    }

    __shared__ float4 rs1[32][8];
    __shared__ float4 rs2[32][8];
    __shared__ float amv[32], scv[32], nbv[32];
    int rg = tid >> 3, c4l = tid & 7;
    size_t coff = (size_t)part*32 + c4l*4;
    float4 s1 = {0.f,0.f,0.f,0.f}, s2 = {0.f,0.f,0.f,0.f};
    for (int i = rg; i < n; i += 32){
        const float4 vv = *(const float4*)&v[(size_t)(s+i)*HD + coff];
        s1.x += vv.x; s1.y += vv.y; s1.z += vv.z; s1.w += vv.w;
        s2.x += vv.x*vv.x; s2.y += vv.y*vv.y; s2.z += vv.z*vv.z; s2.w += vv.w*vv.w;
    }
    rs1[rg][c4l] = s1; rs2[rg][c4l] = s2;
    __syncthreads();
    if (tid < 8){
        float4 t1 = {0.f,0.f,0.f,0.f}, t2 = {0.f,0.f,0.f,0.f};
        for (int r = 0; r < 32; ++r){
            float4 a = rs1[r][tid]; float4 b = rs2[r][tid];
            t1.x += a.x; t1.y += a.y; t1.z += a.z; t1.w += a.w;
            t2.x += b.x; t2.y += b.y; t2.z += b.z; t2.w += b.w;
        }
        float fn = (float)n;
        float S1[4] = {t1.x,t1.y,t1.z,t1.w};
        float S2[4] = {t2.x,t2.y,t2.z,t2.w};
        #pragma unroll
        for (int e = 0; e < 4; ++e){
            int j = part*32 + tid*4 + e;
            float m = S1[e]/fn;
            float aj = na[j];
            float var = S2[e]/fn - (2.f*aj - aj*aj)*m*m;
            float stdv = sqrtf(var + 1e-5f);
            amv[tid*4+e] = aj*m;
            scv[tid*4+e] = nw[j]/stdv;
            nbv[tid*4+e] = nb[j];
        }
    }
    __syncthreads();
    const float4 am4 = *(const float4*)&amv[c4l*4];
    const float4 sc4 = *(const float4*)&scv[c4l*4];
    const float4 nb4 = *(const float4*)&nbv[c4l*4];
    for (int i = rg; i < n; i += 32){
        const float4 vv = *(const float4*)&v[(size_t)(s+i)*HD + coff];
        float4 r;
        r.x = fmaxf((vv.x - am4.x)*sc4.x + nb4.x, 0.f);
        r.y = fmaxf((vv.y - am4.y)*sc4.y + nb4.y, 0.f);
        r.z = fmaxf((vv.z - am4.z)*sc4.z + nb4.z, 0.f);
        r.w = fmaxf((vv.w - am4.w)*sc4.w + nb4.w, 0.f);
        *(float4*)&hout[(size_t)(s+i)*HD + coff] = r;
    }
}

// ---------- fused final: column-sum + logits GEMM + final importance --------
__global__ __launch_bounds__(1024) void k_logits(
    const float* __restrict__ h, const int* __restrict__ gstart,
    const float* __restrict__ fW, const float* __restrict__ fb,
    const float* __restrict__ imp0, const float* __restrict__ impf,
    float* __restrict__ outp)
{
    __shared__ float4 rs1[32][32];
    __shared__ float gsum[HD];
    __shared__ float redn[32];
    int g = blockIdx.x;
    int s = gstart[g], n = gstart[g+1] - s;
    int tid = threadIdx.x;
    int c4 = tid & 31, rg = tid >> 5;
    float4 s1 = {0.f,0.f,0.f,0.f};
    for (int i = rg; i < n; i += 32){
        const float4 vv = *(const float4*)&h[(size_t)(s+i)*HD + c4*4];
        s1.x += vv.x; s1.y += vv.y; s1.z += vv.z; s1.w += vv.w;
    }
    rs1[rg][c4] = s1;
    __syncthreads();
    if (tid < 32){
        float4 t1 = {0.f,0.f,0.f,0.f};
        for (int r = 0; r < 32; ++r){
            float4 a = rs1[r][tid];
            t1.x += a.x; t1.y += a.y; t1.z += a.z; t1.w += a.w;
        }
        gsum[tid*4+0] = t1.x; gsum[tid*4+1] = t1.y;
        gsum[tid*4+2] = t1.z; gsum[tid*4+3] = t1.w;
    }
    __syncthreads();
    if (tid < 32){
        int o = tid;
        float acc = 0.f;
        for (int k = 0; k < HD; ++k) acc = fmaf(gsum[k], fW[k*32 + o], acc);
        outp[g*32 + o] = acc/(float)n + fb[o];
    }
    float val = 0.f;
    bool has = (tid < n);
    float lmn = 3.4e38f, lmx = -3.4e38f;
    if (has){ val = imp0[s+tid] + impf[s+tid]; lmn = val; lmx = val; }
    #pragma unroll
    for (int off = 32; off > 0; off >>= 1){
        lmn = fminf(lmn, __shfl_xor(lmn, off));
        lmx = fmaxf(lmx, __shfl_xor(lmx, off));
    }
    int wv = tid >> 6, lane = tid & 63;
    if (lane == 0){ redn[wv] = lmn; redn[16+wv] = lmx; }
    __syncthreads();
    float lo = redn[0], hi = redn[16];
    for (int r2 = 1; r2 < 16; ++r2){
        lo = fminf(lo, redn[r2]); hi = fmaxf(hi, redn[16+r2]);
    }
    if (has) outp[NG*32 + s + tid] = (val - lo)/(hi - lo + 1e-8f);
}

extern "C" void kernel_launch(void* const* d_in, const int* in_sizes, int n_in,
                              void* d_out, int out_size, void* d_ws, size_t ws_size,
                              hipStream_t stream){
    const float* x    = (const float*)d_in[0];
    const float* imp0 = (const float*)d_in[2];
    const float* pW   = (const float*)d_in[3];
    const float* pb   = (const float*)d_in[4];
    const float* iW   = (const float*)d_in[5];
    const float* ib   = (const float*)d_in[6];
    const float* msgW = (const float*)d_in[7];
    const float* msgb = (const float*)d_in[8];
    const float* updW = (const float*)d_in[9];
    const float* updb = (const float*)d_in[10];
    const float* gWt  = (const float*)d_in[11];
    const float* gb   = (const float*)d_in[12];
    const float* prW  = (const float*)d_in[13];
    const float* prb  = (const float*)d_in[14];
    const float* nw   = (const float*)d_in[15];
    const float* nb   = (const float*)d_in[16];
    const float* na   = (const float*)d_in[17];
    const float* fW   = (const float*)d_in[18];
    const float* fb   = (const float*)d_in[19];
    const int* eidx   = (const int*)d_in[20];
    const int* batch  = (const int*)d_in[21];
    const int* esrc = eidx;
    const int* edst = eidx + NE;
    float* outp = (float*)d_out;

    char* w = (char*)d_ws;
    size_t off = 0;
    auto alloc = [&](size_t bytes)->char*{
        char* p = w + off;
        off += (bytes + 255) & ~(size_t)255;
        return p;
    };
    float* h     = (float*)alloc((size_t)NN*HD*4);
    float* aggB  = (float*)alloc((size_t)NN*HD*4);
    float* outA  = (float*)alloc((size_t)NN*HD*4);
    float* ta    = (float*)alloc((size_t)NN*4);
    float* imp   = (float*)alloc((size_t)NN*4);
    float* W0    = (float*)alloc((size_t)(FT+1)*HD*4);
    float* b0    = (float*)alloc((size_t)HD*4);
    float* Wf    = (float*)alloc((size_t)NLAYERS*2*HD*HD*4);
    float* bcv   = (float*)alloc((size_t)NLAYERS*HD*4);
    int* gstart  = (int*)alloc((size_t)(NG+1)*4);
    int* deg     = (int*)alloc((size_t)NN*4);
    int* rowst   = (int*)alloc((size_t)(NN+1)*4);
    int* cursor  = (int*)alloc((size_t)NN*4);
    int* csr     = (int*)alloc((size_t)NE*4);

    // graph boundaries
    k_gbounds<<<196, 256, 0, stream>>>(batch, gstart);

    // CSR by dst
    hipMemsetAsync(deg, 0, NN*4, stream);
    k_deg<<<3125, 256, 0, stream>>>(edst, deg);
    k_scan<<<1, 1024, 0, stream>>>(deg, rowst);
    k_copy_int<<<196, 256, 0, stream>>>(rowst, cursor, NN);
    k_fill<<<3125, 256, 0, stream>>>(esrc, edst, cursor, csr);

    // weight folds
    k_fold_init<<<1, 128, 0, stream>>>(pW, pb, iW, ib, W0, b0);
    k_fold_layer<<<dim3(257, NLAYERS), 128, 0, stream>>>(msgW, updW, msgb, Wf, bcv);

    // importance = normalize(imp0); h = init GEMM
    k_norm_graph<<<NG, 256, 0, stream>>>(imp0, gstart, imp);
    k_init<<<NBLK, 256, 0, stream>>>(x, imp, W0, b0, h);

    for (int l = 0; l < NLAYERS; ++l){
        k_aggregate<<<6250, 256, 0, stream>>>(h, rowst, csr, aggB);
        k_layer<<<NBLK, 256, 0, stream>>>(
            h, aggB, imp, deg,
            Wf + (size_t)l*2*HD*HD, bcv + (size_t)l*HD,
            updb + (size_t)l*HD, gWt + (size_t)l*(HD+1)*HD, gb + (size_t)l*HD,
            prW + (size_t)l*HD, prb + l, outA, ta);
        k_gnorm<<<dim3(NG,5), 256, 0, stream>>>(outA, gstart,
            nw + (size_t)l*HD, nb + (size_t)l*HD, na + (size_t)l*HD, h, ta, imp);
    }

    // logits + final importance
    k_logits<<<NG, 1024, 0, stream>>>(h, gstart, fW, fb, imp0, imp, outp);
}

// Round 9
// 777.836 us; speedup vs baseline: 1.1443x; 1.1443x over previous
//
#include <hip/hip_runtime.h>
#include <cstdint>

#define NN 50000
#define NE 800000
#define NG 64
#define HD 128
#define FT 64
#define NLAYERS 3
#define MB 32
#define NBLK 1563   // ceil(NN/MB)

// ---------- async global->LDS DMA (16B per lane) ----------
__device__ __forceinline__ void dma16(const float* g, float* l){
    __builtin_amdgcn_global_load_lds(
        (const __attribute__((address_space(1))) void*)g,
        (__attribute__((address_space(3))) void*)l, 16, 0, 0);
}

// ---------- graph boundaries (batch is sorted contiguous runs) ----------
__global__ void k_gbounds(const int* __restrict__ batch, int* __restrict__ gstart){
    int i = blockIdx.x*blockDim.x + threadIdx.x;
    if (i >= NN) return;
    int g = batch[i];
    if (i == 0){ for (int q = 0; q <= g; ++q) gstart[q] = 0; }
    else { int gp = batch[i-1]; for (int q = gp+1; q <= g; ++q) gstart[q] = i; }
    if (i == NN-1){ for (int q = g+1; q <= NG; ++q) gstart[q] = NN; }
}

// ---------- block-wide min/max reduce helper (256 threads = 4 waves) ----------
__device__ __forceinline__ void block_minmax(float lmn, float lmx, float* red,
                                             float& omn, float& omx){
    #pragma unroll
    for (int off = 32; off > 0; off >>= 1){
        lmn = fminf(lmn, __shfl_xor(lmn, off));
        lmx = fmaxf(lmx, __shfl_xor(lmx, off));
    }
    int wave = threadIdx.x >> 6;
    if ((threadIdx.x & 63) == 0){ red[wave] = lmn; red[4+wave] = lmx; }
    __syncthreads();
    omn = fminf(fminf(red[0], red[1]), fminf(red[2], red[3]));
    omx = fmaxf(fmaxf(red[4], red[5]), fmaxf(red[6], red[7]));
    __syncthreads();
}

// ---------- per-graph normalize (initial importance only) ----------
__global__ __launch_bounds__(256) void k_norm_graph(
    const float* __restrict__ va, const int* __restrict__ gstart,
    float* __restrict__ out)
{
    __shared__ float sv[1024];
    __shared__ float red[8];
    int g = blockIdx.x;
    int s = gstart[g], n = gstart[g+1] - s;
    int tid = threadIdx.x;
    float lmn = 3.4e38f, lmx = -3.4e38f;
    for (int i = tid; i < n; i += 256){
        float v = va[s+i];
        sv[i] = v;
        lmn = fminf(lmn, v); lmx = fmaxf(lmx, v);
    }
    float lo, hi;
    block_minmax(lmn, lmx, red, lo, hi);
    float inv = 1.f/(hi - lo + 1e-8f);
    for (int i = tid; i < n; i += 256) out[s+i] = (sv[i] - lo)*inv;
}

// Fold imp_proj into init_W: W0 is (FT+1) x HD, b0 = init_b + pb @ init_W[FT:]
__global__ void k_fold_init(const float* __restrict__ pW, const float* __restrict__ pb,
                            const float* __restrict__ iW, const float* __restrict__ ib,
                            float* __restrict__ W0, float* __restrict__ b0){
    int j = threadIdx.x;
    for (int k = 0; k < FT; ++k) W0[k*HD + j] = iW[k*HD + j];
    float w2 = 0.f, b2 = 0.f;
    for (int k = 0; k < HD; ++k){
        float w = iW[(FT + k)*HD + j];
        w2 += pW[k]*w;
        b2 += pb[k]*w;
    }
    W0[FT*HD + j] = w2;
    b0[j] = ib[j] + b2;
}

// Wf(256x128) = [uW_top ; msg_W @ uW_bot], bcv = msg_b @ uW_bot.
// grid (257, NLAYERS) x 128.
__global__ void k_fold_layer(const float* __restrict__ msgW, const float* __restrict__ updW,
                             const float* __restrict__ msgb,
                             float* __restrict__ WfA, float* __restrict__ bcvA){
    int l = blockIdx.y;
    const float* mW  = msgW + (size_t)l*HD*HD;
    const float* uW  = updW + (size_t)l*2*HD*HD;
    const float* mb  = msgb + (size_t)l*HD;
    float* Wf  = WfA  + (size_t)l*2*HD*HD;
    float* bcv = bcvA + (size_t)l*HD;
    int j = threadIdx.x;
    int r = blockIdx.x;
    if (r < HD){
        Wf[(size_t)r*HD + j] = uW[(size_t)r*HD + j];
    } else if (r < 2*HD){
        int rr = r - HD;
        const float* uWbot = uW + (size_t)HD*HD;
        float acc = 0.f;
        for (int k = 0; k < HD; ++k)
            acc = fmaf(mW[(size_t)rr*HD + k], uWbot[(size_t)k*HD + j], acc);
        Wf[(size_t)r*HD + j] = acc;
    } else {
        const float* uWbot = uW + (size_t)HD*HD;
        float acc = 0.f;
        for (int k = 0; k < HD; ++k)
            acc = fmaf(mb[k], uWbot[(size_t)k*HD + j], acc);
        bcv[j] = acc;
    }
}

// ---------- init GEMM: h = x @ W0[0:64] + imp*W0[64] + b0 ----------
__global__ __launch_bounds__(256) void k_init(
    const float* __restrict__ x, const float* __restrict__ imp,
    const float* __restrict__ W0, const float* __restrict__ b0v,
    float* __restrict__ h)
{
    __shared__ float lds[MB][FT];
    __shared__ float scs[MB];
    int base = blockIdx.x*MB, tid = threadIdx.x;
    #pragma unroll
    for (int i = 0; i < 2; ++i){
        int fidx = i*256 + tid;
        int t = fidx >> 4, c = fidx & 15;
        float4 v = {0.f,0.f,0.f,0.f};
        if (base + t < NN) v = *(const float4*)&x[(size_t)(base+t)*FT + c*4];
        *(float4*)&lds[t][c*4] = v;
    }
    if (tid < MB) scs[tid] = (base+tid < NN) ? imp[base+tid] : 0.f;
    __syncthreads();

    const int cg = tid & 31, rg = tid >> 5;
    const int c0 = cg*4, r0 = rg*4;
    const float4 wl4 = *(const float4*)&W0[(size_t)FT*HD + c0];
    const float4 b4  = *(const float4*)&b0v[c0];
    float acc[4][4];
    #pragma unroll
    for (int r = 0; r < 4; ++r){
        float s = scs[r0+r];
        acc[r][0] = fmaf(s, wl4.x, b4.x); acc[r][1] = fmaf(s, wl4.y, b4.y);
        acc[r][2] = fmaf(s, wl4.z, b4.z); acc[r][3] = fmaf(s, wl4.w, b4.w);
    }
    #pragma unroll 4
    for (int k4 = 0; k4 < 16; ++k4){
        const float4 w0 = *(const float4*)&W0[(size_t)(k4*4+0)*HD + c0];
        const float4 w1 = *(const float4*)&W0[(size_t)(k4*4+1)*HD + c0];
        const float4 w2 = *(const float4*)&W0[(size_t)(k4*4+2)*HD + c0];
        const float4 w3 = *(const float4*)&W0[(size_t)(k4*4+3)*HD + c0];
        #pragma unroll
        for (int r = 0; r < 4; ++r){
            const float4 a = *(const float4*)&lds[r0+r][k4*4];
            acc[r][0]=fmaf(a.x,w0.x,fmaf(a.y,w1.x,fmaf(a.z,w2.x,fmaf(a.w,w3.x,acc[r][0]))));
            acc[r][1]=fmaf(a.x,w0.y,fmaf(a.y,w1.y,fmaf(a.z,w2.y,fmaf(a.w,w3.y,acc[r][1]))));
            acc[r][2]=fmaf(a.x,w0.z,fmaf(a.y,w1.z,fmaf(a.z,w2.z,fmaf(a.w,w3.z,acc[r][2]))));
            acc[r][3]=fmaf(a.x,w0.w,fmaf(a.y,w1.w,fmaf(a.z,w2.w,fmaf(a.w,w3.w,acc[r][3]))));
        }
    }
    #pragma unroll
    for (int r = 0; r < 4; ++r)
        if (base + r0 + r < NN)
            *(float4*)&h[(size_t)(base+r0+r)*HD + c0] =
                make_float4(acc[r][0], acc[r][1], acc[r][2], acc[r][3]);
}

// FMA micro-step: 8 k-rows (two lds float4s a,b; weights w0..w7) into acc[r][*]
#define FMA8(r, a, b, W0_,W1_,W2_,W3_,W4_,W5_,W6_,W7_, A) \
    A[r][0]=fmaf((b).x,W4_.x,fmaf((b).y,W5_.x,fmaf((b).z,W6_.x,fmaf((b).w,W7_.x, \
            fmaf((a).x,W0_.x,fmaf((a).y,W1_.x,fmaf((a).z,W2_.x,fmaf((a).w,W3_.x,A[r][0])))))))); \
    A[r][1]=fmaf((b).x,W4_.y,fmaf((b).y,W5_.y,fmaf((b).z,W6_.y,fmaf((b).w,W7_.y, \
            fmaf((a).x,W0_.y,fmaf((a).y,W1_.y,fmaf((a).z,W2_.y,fmaf((a).w,W3_.y,A[r][1])))))))); \
    A[r][2]=fmaf((b).x,W4_.z,fmaf((b).y,W5_.z,fmaf((b).z,W6_.z,fmaf((b).w,W7_.z, \
            fmaf((a).x,W0_.z,fmaf((a).y,W1_.z,fmaf((a).z,W2_.z,fmaf((a).w,W3_.z,A[r][2])))))))); \
    A[r][3]=fmaf((b).x,W4_.w,fmaf((b).y,W5_.w,fmaf((b).z,W6_.w,fmaf((b).w,W7_.w, \
            fmaf((a).x,W0_.w,fmaf((a).y,W1_.w,fmaf((a).z,W2_.w,fmaf((a).w,W3_.w,A[r][3]))))))));

// ---------- per-layer mega kernel: all staging via global_load_lds DMA ------
// LDS: hl 16K + al 16K + wbuf 2x16K = 64.4KB -> 2 blocks/CU.
__global__ __launch_bounds__(256, 2) void k_layer(
    const float* __restrict__ h, const float* __restrict__ aggr,
    const float* __restrict__ imp, const int* __restrict__ deg,
    const float* __restrict__ Wf, const float* __restrict__ bcv,
    const float* __restrict__ ub,
    const float* __restrict__ gW, const float* __restrict__ gb,
    const float* __restrict__ prW, const float* __restrict__ prb,
    float* __restrict__ outbuf, float* __restrict__ ta)
{
    __shared__ float hl[MB][HD];        // h tile
    __shared__ float al[MB][HD];        // aggr tile, later conv
    __shared__ float wbuf[2][32][HD];   // double-buffered weight K-tile
    __shared__ float scs[MB];
    __shared__ float dgs[MB];
    __shared__ float red[8][4];
    const int base = blockIdx.x*MB, tid = threadIdx.x;

    // stage act tiles via DMA (rows base..base+31; OOB rows read adjacent ws
    // buffers — values unused, writes guarded)
    {
        const float* hsrc = h    + (size_t)base*HD;
        const float* asrc = aggr + (size_t)base*HD;
        #pragma unroll
        for (int i = 0; i < 4; ++i){
            dma16(hsrc + i*1024 + tid*4, &hl[0][0] + i*1024 + tid*4);
            dma16(asrc + i*1024 + tid*4, &al[0][0] + i*1024 + tid*4);
        }
    }
    // stage conv weight tile 0
    #pragma unroll
    for (int i = 0; i < 4; ++i)
        dma16(Wf + i*1024 + tid*4, &wbuf[0][0][0] + i*1024 + tid*4);
    if (tid < MB) scs[tid] = (base+tid < NN) ? imp[base+tid] : 0.f;
    else if (tid < 2*MB){
        int t = tid - MB;
        dgs[t] = (base+t < NN) ? (float)deg[base+t] : 0.f;
    }

    const int cg = tid & 31, rg = tid >> 5;
    const int c0 = cg*4, r0 = rg*4;
    const float4 bc4 = *(const float4*)&bcv[c0];
    const float4 ub4 = *(const float4*)&ub[c0];
    const float4 gwl = *(const float4*)&gW[(size_t)HD*HD + c0];
    const float4 gb4 = *(const float4*)&gb[c0];
    const float4 pr4 = *(const float4*)&prW[c0];

    __syncthreads();   // compiler drains vmcnt: act + wtile0 ready

    // ---- conv = [h|aggr] @ Wf + deg*bc + ub  (8 tiles of 32 K-rows)
    float acc[4][4];
    #pragma unroll
    for (int r = 0; r < 4; ++r){
        float d = dgs[r0+r];
        acc[r][0] = fmaf(d, bc4.x, ub4.x); acc[r][1] = fmaf(d, bc4.y, ub4.y);
        acc[r][2] = fmaf(d, bc4.z, ub4.z); acc[r][3] = fmaf(d, bc4.w, ub4.w);
    }
    for (int t = 0; t < 8; ++t){
        // prefetch next tile (tile t+1, or gate tile 0 at t==7) into other buf
        {
            const float* nsrc = (t < 7) ? (Wf + (size_t)(t+1)*32*HD) : gW;
            float* ndst = &wbuf[(t+1)&1][0][0];
            #pragma unroll
            for (int i = 0; i < 4; ++i)
                dma16(nsrc + i*1024 + tid*4, ndst + i*1024 + tid*4);
        }
        const float (*A)[HD] = (t < 4) ? hl : al;
        const int kb = (t & 3)*32;
        const float (*W)[HD] = wbuf[t & 1];
        #pragma unroll
        for (int kk = 0; kk < 32; kk += 8){
            const float4 w0 = *(const float4*)&W[kk+0][c0];
            const float4 w1 = *(const float4*)&W[kk+1][c0];
            const float4 w2 = *(const float4*)&W[kk+2][c0];
            const float4 w3 = *(const float4*)&W[kk+3][c0];
            const float4 w4 = *(const float4*)&W[kk+4][c0];
            const float4 w5 = *(const float4*)&W[kk+5][c0];
            const float4 w6 = *(const float4*)&W[kk+6][c0];
            const float4 w7 = *(const float4*)&W[kk+7][c0];
            #pragma unroll
            for (int r = 0; r < 4; ++r){
                const float4 a = *(const float4*)&A[r0+r][kb+kk];
                const float4 b = *(const float4*)&A[r0+r][kb+kk+4];
                FMA8(r, a, b, w0,w1,w2,w3,w4,w5,w6,w7, acc)
            }
        }
        __syncthreads();   // drains next-tile DMA; all reads of cur tile done
    }

    // stash conv into al (all conv reads of al finished at last barrier);
    // prefetch gate tile 1 into wbuf[1]
    #pragma unroll
    for (int r = 0; r < 4; ++r)
        *(float4*)&al[r0+r][c0] = make_float4(acc[r][0],acc[r][1],acc[r][2],acc[r][3]);
    {
        const float* nsrc = gW + (size_t)32*HD;
        #pragma unroll
        for (int i = 0; i < 4; ++i)
            dma16(nsrc + i*1024 + tid*4, &wbuf[1][0][0] + i*1024 + tid*4);
    }
    __syncthreads();   // conv visible; gate tile 1 ready (tile 0 already was)

    // ---- gate z = conv@gW_top + imp*gW[128] + gb  (4 tiles of 32 K-rows)
    float z[4][4];
    #pragma unroll
    for (int r = 0; r < 4; ++r){
        float s = scs[r0+r];
        z[r][0] = fmaf(s, gwl.x, gb4.x); z[r][1] = fmaf(s, gwl.y, gb4.y);
        z[r][2] = fmaf(s, gwl.z, gb4.z); z[r][3] = fmaf(s, gwl.w, gb4.w);
    }
    for (int t = 0; t < 4; ++t){
        if (t < 2){   // tiles t+2 still to fetch (t+1 already in flight/ready)
            const float* nsrc = gW + (size_t)(t+2)*32*HD;
            float* ndst = &wbuf[t&1][0][0];
            // careful: wbuf[t&1] is being read THIS iteration — prefetch must
            // go to the buffer freed LAST iteration; schedule below instead
            (void)nsrc; (void)ndst;
        }
        // prefetch tile t+2 into the buffer being read this iteration is
        // unsafe; prefetch tile t+1's successor pattern: issue tile t+2 into
        // wbuf[(t+2)&1] == wbuf[t&1] AFTER this iteration's reads — simplest
        // correct form: issue next-needed tile (t+1 is ready; issue t+2) at
        // the NEXT iteration top. Here: issue nothing extra; fall back to
        // issuing tile t+2 during iteration t+1 via the (t<2) branch below.
        const float (*W)[HD] = wbuf[t & 1];
        const int kb = t*32;
        #pragma unroll
        for (int kk = 0; kk < 32; kk += 8){
            const float4 w0 = *(const float4*)&W[kk+0][c0];
            const float4 w1 = *(const float4*)&W[kk+1][c0];
            const float4 w2 = *(const float4*)&W[kk+2][c0];
            const float4 w3 = *(const float4*)&W[kk+3][c0];
            const float4 w4 = *(const float4*)&W[kk+4][c0];
            const float4 w5 = *(const float4*)&W[kk+5][c0];
            const float4 w6 = *(const float4*)&W[kk+6][c0];
            const float4 w7 = *(const float4*)&W[kk+7][c0];
            #pragma unroll
            for (int r = 0; r < 4; ++r){
                const float4 a = *(const float4*)&al[r0+r][kb+kk];
                const float4 b = *(const float4*)&al[r0+r][kb+kk+4];
                FMA8(r, a, b, w0,w1,w2,w3,w4,w5,w6,w7, z)
            }
        }
        __syncthreads();   // reads of wbuf[t&1] done
        if (t < 2){        // now wbuf[t&1] is free: stage tile t+2 into it
            const float* nsrc = gW + (size_t)(t+2)*32*HD;
            float* ndst = &wbuf[t&1][0][0];
            #pragma unroll
            for (int i = 0; i < 4; ++i)
                dma16(nsrc + i*1024 + tid*4, ndst + i*1024 + tid*4);
            // drained by the barrier at end of iteration t+1
        }
    }

    // epilogue: gate mix, store out, prop partials (conv still in acc regs)
    float psum[4];
    #pragma unroll
    for (int r = 0; r < 4; ++r){
        const float4 hv = *(const float4*)&hl[r0+r][c0];
        float g0 = 1.f/(1.f + expf(-z[r][0]));
        float g1 = 1.f/(1.f + expf(-z[r][1]));
        float g2 = 1.f/(1.f + expf(-z[r][2]));
        float g3 = 1.f/(1.f + expf(-z[r][3]));
        float o0 = g0*acc[r][0] + (1.f-g0)*hv.x;
        float o1 = g1*acc[r][1] + (1.f-g1)*hv.y;
        float o2 = g2*acc[r][2] + (1.f-g2)*hv.z;
        float o3 = g3*acc[r][3] + (1.f-g3)*hv.w;
        if (base + r0 + r < NN)
            *(float4*)&outbuf[(size_t)(base+r0+r)*HD + c0] = make_float4(o0,o1,o2,o3);
        psum[r] = o0*pr4.x + o1*pr4.y + o2*pr4.z + o3*pr4.w;
    }
    #pragma unroll
    for (int r = 0; r < 4; ++r){
        float v = psum[r];
        #pragma unroll
        for (int off = 16; off > 0; off >>= 1) v += __shfl_xor(v, off);
        if (cg == 0) red[rg][r] = v;
    }
    __syncthreads();
    if (tid < MB && base + tid < NN)
        ta[base+tid] = 0.9f*scs[tid] + 0.1f*(red[tid>>2][tid&3] + prb[0]);
}

// ---------- CSR build (by dst) ----------
__global__ void k_deg(const int* __restrict__ dst, int* deg){
    int e = blockIdx.x*blockDim.x + threadIdx.x;
    if (e < NE) atomicAdd(&deg[dst[e]], 1);
}

__global__ __launch_bounds__(1024) void k_scan(const int* __restrict__ deg,
                                               int* __restrict__ rowstart){
    __shared__ int wtot[16];
    __shared__ int woff[16];
    __shared__ int carry;
    int tid = threadIdx.x, lane = tid & 63, wv = tid >> 6;
    if (tid == 0) carry = 0;
    __syncthreads();
    for (int base = 0; base < NN; base += 1024){
        int i = base + tid;
        int v = (i < NN) ? deg[i] : 0;
        int x = v;
        #pragma unroll
        for (int off = 1; off < 64; off <<= 1){
            int y = __shfl_up(x, off);
            if (lane >= off) x += y;
        }
        if (lane == 63) wtot[wv] = x;
        __syncthreads();
        if (tid == 0){
            int a = carry;
            for (int w2 = 0; w2 < 16; ++w2){ woff[w2] = a; a += wtot[w2]; }
            carry = a;
        }
        __syncthreads();
        if (i < NN) rowstart[i] = woff[wv] + x - v;   // exclusive
    }
    __syncthreads();
    if (tid == 0) rowstart[NN] = carry;
}

__global__ void k_copy_int(const int* __restrict__ a, int* __restrict__ b, int n){
    int i = blockIdx.x*blockDim.x + threadIdx.x;
    if (i < n) b[i] = a[i];
}

__global__ void k_fill(const int* __restrict__ src, const int* __restrict__ dst,
                       int* cursor, int* __restrict__ csr){
    int e = blockIdx.x*blockDim.x + threadIdx.x;
    if (e < NE){
        int d = dst[e];
        int p = atomicAdd(&cursor[d], 1);
        csr[p] = src[e];
    }
}

// aggr[node] = sum over in-edges of h[src]; 32 lanes/node, 8-edge ILP
__global__ __launch_bounds__(256) void k_aggregate(
    const float* __restrict__ hm, const int* __restrict__ rowstart,
    const int* __restrict__ csr, float* __restrict__ aggr)
{
    int node = blockIdx.x*8 + (threadIdx.x >> 5);
    int lane = threadIdx.x & 31;
    float4 a0 = {0.f,0.f,0.f,0.f}, a1 = a0, a2 = a0, a3 = a0;
    float4 a4 = a0, a5 = a0, a6 = a0, a7 = a0;
    int e0 = rowstart[node], e1 = rowstart[node+1];
    int e = e0;
    for (; e + 7 < e1; e += 8){
        int s0 = csr[e],   s1 = csr[e+1], s2 = csr[e+2], s3 = csr[e+3];
        int s4 = csr[e+4], s5 = csr[e+5], s6 = csr[e+6], s7 = csr[e+7];
        const float4 v0 = *(const float4*)&hm[(size_t)s0*HD + lane*4];
        const float4 v1 = *(const float4*)&hm[(size_t)s1*HD + lane*4];
        const float4 v2 = *(const float4*)&hm[(size_t)s2*HD + lane*4];
        const float4 v3 = *(const float4*)&hm[(size_t)s3*HD + lane*4];
        const float4 v4 = *(const float4*)&hm[(size_t)s4*HD + lane*4];
        const float4 v5 = *(const float4*)&hm[(size_t)s5*HD + lane*4];
        const float4 v6 = *(const float4*)&hm[(size_t)s6*HD + lane*4];
        const float4 v7 = *(const float4*)&hm[(size_t)s7*HD + lane*4];
        a0.x += v0.x; a0.y += v0.y; a0.z += v0.z; a0.w += v0.w;
        a1.x += v1.x; a1.y += v1.y; a1.z += v1.z; a1.w += v1.w;
        a2.x += v2.x; a2.y += v2.y; a2.z += v2.z; a2.w += v2.w;
        a3.x += v3.x; a3.y += v3.y; a3.z += v3.z; a3.w += v3.w;
        a4.x += v4.x; a4.y += v4.y; a4.z += v4.z; a4.w += v4.w;
        a5.x += v5.x; a5.y += v5.y; a5.z += v5.z; a5.w += v5.w;
        a6.x += v6.x; a6.y += v6.y; a6.z += v6.z; a6.w += v6.w;
        a7.x += v7.x; a7.y += v7.y; a7.z += v7.z; a7.w += v7.w;
    }
    for (; e + 3 < e1; e += 4){
        int s0 = csr[e], s1 = csr[e+1], s2 = csr[e+2], s3 = csr[e+3];
        const float4 v0 = *(const float4*)&hm[(size_t)s0*HD + lane*4];
        const float4 v1 = *(const float4*)&hm[(size_t)s1*HD + lane*4];
        const float4 v2 = *(const float4*)&hm[(size_t)s2*HD + lane*4];
        const float4 v3 = *(const float4*)&hm[(size_t)s3*HD + lane*4];
        a0.x += v0.x; a0.y += v0.y; a0.z += v0.z; a0.w += v0.w;
        a1.x += v1.x; a1.y += v1.y; a1.z += v1.z; a1.w += v1.w;
        a2.x += v2.x; a2.y += v2.y; a2.z += v2.z; a2.w += v2.w;
        a3.x += v3.x; a3.y += v3.y; a3.z += v3.z; a3.w += v3.w;
    }
    for (; e < e1; ++e){
        int s0 = csr[e];
        const float4 v0 = *(const float4*)&hm[(size_t)s0*HD + lane*4];
        a0.x += v0.x; a0.y += v0.y; a0.z += v0.z; a0.w += v0.w;
    }
    a0.x += a1.x; a0.y += a1.y; a0.z += a1.z; a0.w += a1.w;
    a2.x += a3.x; a2.y += a3.y; a2.z += a3.z; a2.w += a3.w;
    a4.x += a5.x; a4.y += a5.y; a4.z += a5.z; a4.w += a5.w;
    a6.x += a7.x; a6.y += a7.y; a6.z += a7.z; a6.w += a7.w;
    a0.x += a2.x; a0.y += a2.y; a0.z += a2.z; a0.w += a2.w;
    a4.x += a6.x; a4.y += a6.y; a4.z += a6.z; a4.w += a6.w;
    a0.x += a4.x; a0.y += a4.y; a0.z += a4.z; a0.w += a4.w;
    *(float4*)&aggr[(size_t)node*HD + lane*4] = a0;
}

// ---------- fused graph-norm (4 col-slices per graph) + importance chain ----
__global__ __launch_bounds__(256) void k_gnorm(
    const float* __restrict__ v, const int* __restrict__ gstart,
    const float* __restrict__ nw, const float* __restrict__ nb,
    const float* __restrict__ na, float* __restrict__ hout,
    const float* __restrict__ tsrc, float* __restrict__ tdst)
{
    int g = blockIdx.x;
    int part = blockIdx.y;
    int s = gstart[g], n = gstart[g+1] - s;
    int tid = threadIdx.x;

    if (part == 4){
        __shared__ float sv[1024];
        __shared__ float red[8];
        float lmn = 3.4e38f, lmx = -3.4e38f;
        for (int i = tid; i < n; i += 256){
            float val = tsrc[s+i]; sv[i] = val;
            lmn = fminf(lmn, val); lmx = fmaxf(lmx, val);
        }
        float lo, hi;
        block_minmax(lmn, lmx, red, lo, hi);
        float inv = 1.f/(hi - lo + 1e-8f);
        lmn = 3.4e38f; lmx = -3.4e38f;
        for (int i = tid; i < n; i += 256){
            float t2 = (sv[i] - lo)*inv;
            if (t2 < 0.1f) t2 = 0.f;
            sv[i] = t2;
            lmn = fminf(lmn, t2); lmx = fmaxf(lmx, t2);
        }
        float lo2, hi2;
        block_minmax(lmn, lmx, red, lo2, hi2);
        float inv2 = 1.f/(hi2 - lo2 + 1e-8f);
        for (int i = tid; i < n; i += 256) tdst[s+i] = (sv[i] - lo2)*inv2;
        return;
    }

    __shared__ float4 rs1[32][8];
    __shared__ float4 rs2[32][8];
    __shared__ float amv[32], scv[32], nbv[32];
    int rg = tid >> 3, c4l = tid & 7;
    size_t coff = (size_t)part*32 + c4l*4;
    float4 s1 = {0.f,0.f,0.f,0.f}, s2 = {0.f,0.f,0.f,0.f};
    for (int i = rg; i < n; i += 32){
        const float4 vv = *(const float4*)&v[(size_t)(s+i)*HD + coff];
        s1.x += vv.x; s1.y += vv.y; s1.z += vv.z; s1.w += vv.w;
        s2.x += vv.x*vv.x; s2.y += vv.y*vv.y; s2.z += vv.z*vv.z; s2.w += vv.w*vv.w;
    }
    rs1[rg][c4l] = s1; rs2[rg][c4l] = s2;
    __syncthreads();
    if (tid < 8){
        float4 t1 = {0.f,0.f,0.f,0.f}, t2 = {0.f,0.f,0.f,0.f};
        for (int r = 0; r < 32; ++r){
            float4 a = rs1[r][tid]; float4 b = rs2[r][tid];
            t1.x += a.x; t1.y += a.y; t1.z += a.z; t1.w += a.w;
            t2.x += b.x; t2.y += b.y; t2.z += b.z; t2.w += b.w;
        }
        float fn = (float)n;
        float S1[4] = {t1.x,t1.y,t1.z,t1.w};
        float S2[4] = {t2.x,t2.y,t2.z,t2.w};
        #pragma unroll
        for (int e = 0; e < 4; ++e){
            int j = part*32 + tid*4 + e;
            float m = S1[e]/fn;
            float aj = na[j];
            float var = S2[e]/fn - (2.f*aj - aj*aj)*m*m;
            float stdv = sqrtf(var + 1e-5f);
            amv[tid*4+e] = aj*m;
            scv[tid*4+e] = nw[j]/stdv;
            nbv[tid*4+e] = nb[j];
        }
    }
    __syncthreads();
    const float4 am4 = *(const float4*)&amv[c4l*4];
    const float4 sc4 = *(const float4*)&scv[c4l*4];
    const float4 nb4 = *(const float4*)&nbv[c4l*4];
    for (int i = rg; i < n; i += 32){
        const float4 vv = *(const float4*)&v[(size_t)(s+i)*HD + coff];
        float4 r;
        r.x = fmaxf((vv.x - am4.x)*sc4.x + nb4.x, 0.f);
        r.y = fmaxf((vv.y - am4.y)*sc4.y + nb4.y, 0.f);
        r.z = fmaxf((vv.z - am4.z)*sc4.z + nb4.z, 0.f);
        r.w = fmaxf((vv.w - am4.w)*sc4.w + nb4.w, 0.f);
        *(float4*)&hout[(size_t)(s+i)*HD + coff] = r;
    }
}

// ---------- fused final: column-sum + logits GEMM + final importance --------
__global__ __launch_bounds__(1024) void k_logits(
    const float* __restrict__ h, const int* __restrict__ gstart,
    const float* __restrict__ fW, const float* __restrict__ fb,
    const float* __restrict__ imp0, const float* __restrict__ impf,
    float* __restrict__ outp)
{
    __shared__ float4 rs1[32][32];
    __shared__ float gsum[HD];
    __shared__ float redn[32];
    int g = blockIdx.x;
    int s = gstart[g], n = gstart[g+1] - s;
    int tid = threadIdx.x;
    int c4 = tid & 31, rg = tid >> 5;
    float4 s1 = {0.f,0.f,0.f,0.f};
    for (int i = rg; i < n; i += 32){
        const float4 vv = *(const float4*)&h[(size_t)(s+i)*HD + c4*4];
        s1.x += vv.x; s1.y += vv.y; s1.z += vv.z; s1.w += vv.w;
    }
    rs1[rg][c4] = s1;
    __syncthreads();
    if (tid < 32){
        float4 t1 = {0.f,0.f,0.f,0.f};
        for (int r = 0; r < 32; ++r){
            float4 a = rs1[r][tid];
            t1.x += a.x; t1.y += a.y; t1.z += a.z; t1.w += a.w;
        }
        gsum[tid*4+0] = t1.x; gsum[tid*4+1] = t1.y;
        gsum[tid*4+2] = t1.z; gsum[tid*4+3] = t1.w;
    }
    __syncthreads();
    if (tid < 32){
        int o = tid;
        float acc = 0.f;
        for (int k = 0; k < HD; ++k) acc = fmaf(gsum[k], fW[k*32 + o], acc);
        outp[g*32 + o] = acc/(float)n + fb[o];
    }
    float val = 0.f;
    bool has = (tid < n);
    float lmn = 3.4e38f, lmx = -3.4e38f;
    if (has){ val = imp0[s+tid] + impf[s+tid]; lmn = val; lmx = val; }
    #pragma unroll
    for (int off = 32; off > 0; off >>= 1){
        lmn = fminf(lmn, __shfl_xor(lmn, off));
        lmx = fmaxf(lmx, __shfl_xor(lmx, off));
    }
    int wv = tid >> 6, lane = tid & 63;
    if (lane == 0){ redn[wv] = lmn; redn[16+wv] = lmx; }
    __syncthreads();
    float lo = redn[0], hi = redn[16];
    for (int r2 = 1; r2 < 16; ++r2){
        lo = fminf(lo, redn[r2]); hi = fmaxf(hi, redn[16+r2]);
    }
    if (has) outp[NG*32 + s + tid] = (val - lo)/(hi - lo + 1e-8f);
}

extern "C" void kernel_launch(void* const* d_in, const int* in_sizes, int n_in,
                              void* d_out, int out_size, void* d_ws, size_t ws_size,
                              hipStream_t stream){
    const float* x    = (const float*)d_in[0];
    const float* imp0 = (const float*)d_in[2];
    const float* pW   = (const float*)d_in[3];
    const float* pb   = (const float*)d_in[4];
    const float* iW   = (const float*)d_in[5];
    const float* ib   = (const float*)d_in[6];
    const float* msgW = (const float*)d_in[7];
    const float* msgb = (const float*)d_in[8];
    const float* updW = (const float*)d_in[9];
    const float* updb = (const float*)d_in[10];
    const float* gWt  = (const float*)d_in[11];
    const float* gb   = (const float*)d_in[12];
    const float* prW  = (const float*)d_in[13];
    const float* prb  = (const float*)d_in[14];
    const float* nw   = (const float*)d_in[15];
    const float* nb   = (const float*)d_in[16];
    const float* na   = (const float*)d_in[17];
    const float* fW   = (const float*)d_in[18];
    const float* fb   = (const float*)d_in[19];
    const int* eidx   = (const int*)d_in[20];
    const int* batch  = (const int*)d_in[21];
    const int* esrc = eidx;
    const int* edst = eidx + NE;
    float* outp = (float*)d_out;

    char* w = (char*)d_ws;
    size_t off = 0;
    auto alloc = [&](size_t bytes)->char*{
        char* p = w + off;
        off += (bytes + 255) & ~(size_t)255;
        return p;
    };
    float* h     = (float*)alloc((size_t)NN*HD*4);
    float* aggB  = (float*)alloc((size_t)NN*HD*4);
    float* outA  = (float*)alloc((size_t)NN*HD*4);
    float* ta    = (float*)alloc((size_t)NN*4);
    float* imp   = (float*)alloc((size_t)NN*4);
    float* W0    = (float*)alloc((size_t)(FT+1)*HD*4);
    float* b0    = (float*)alloc((size_t)HD*4);
    float* Wf    = (float*)alloc((size_t)NLAYERS*2*HD*HD*4);
    float* bcv   = (float*)alloc((size_t)NLAYERS*HD*4);
    int* gstart  = (int*)alloc((size_t)(NG+1)*4);
    int* deg     = (int*)alloc((size_t)NN*4);
    int* rowst   = (int*)alloc((size_t)(NN+1)*4);
    int* cursor  = (int*)alloc((size_t)NN*4);
    int* csr     = (int*)alloc((size_t)NE*4);

    // graph boundaries
    k_gbounds<<<196, 256, 0, stream>>>(batch, gstart);

    // CSR by dst
    hipMemsetAsync(deg, 0, NN*4, stream);
    k_deg<<<3125, 256, 0, stream>>>(edst, deg);
    k_scan<<<1, 1024, 0, stream>>>(deg, rowst);
    k_copy_int<<<196, 256, 0, stream>>>(rowst, cursor, NN);
    k_fill<<<3125, 256, 0, stream>>>(esrc, edst, cursor, csr);

    // weight folds
    k_fold_init<<<1, 128, 0, stream>>>(pW, pb, iW, ib, W0, b0);
    k_fold_layer<<<dim3(257, NLAYERS), 128, 0, stream>>>(msgW, updW, msgb, Wf, bcv);

    // importance = normalize(imp0); h = init GEMM
    k_norm_graph<<<NG, 256, 0, stream>>>(imp0, gstart, imp);
    k_init<<<NBLK, 256, 0, stream>>>(x, imp, W0, b0, h);

    for (int l = 0; l < NLAYERS; ++l){
        k_aggregate<<<6250, 256, 0, stream>>>(h, rowst, csr, aggB);
        k_layer<<<NBLK, 256, 0, stream>>>(
            h, aggB, imp, deg,
            Wf + (size_t)l*2*HD*HD, bcv + (size_t)l*HD,
            updb + (size_t)l*HD, gWt + (size_t)l*(HD+1)*HD, gb + (size_t)l*HD,
            prW + (size_t)l*HD, prb + l, outA, ta);
        k_gnorm<<<dim3(NG,5), 256, 0, stream>>>(outA, gstart,
            nw + (size_t)l*HD, nb + (size_t)l*HD, na + (size_t)l*HD, h, ta, imp);
    }

    // logits + final importance
    k_logits<<<NG, 1024, 0, stream>>>(h, gstart, fW, fb, imp0, imp, outp);
}

// Round 10
// 689.535 us; speedup vs baseline: 1.2908x; 1.1281x over previous
//
#include <hip/hip_runtime.h>
#include <cstdint>

#define NN 50000
#define NE 800000
#define NG 64
#define HD 128
#define FT 64
#define NLAYERS 3
#define MB 32
#define NBLK 1563   // ceil(NN/MB)

// ---------- graph boundaries (batch is sorted contiguous runs) ----------
__global__ void k_gbounds(const int* __restrict__ batch, int* __restrict__ gstart){
    int i = blockIdx.x*blockDim.x + threadIdx.x;
    if (i >= NN) return;
    int g = batch[i];
    if (i == 0){ for (int q = 0; q <= g; ++q) gstart[q] = 0; }
    else { int gp = batch[i-1]; for (int q = gp+1; q <= g; ++q) gstart[q] = i; }
    if (i == NN-1){ for (int q = g+1; q <= NG; ++q) gstart[q] = NN; }
}

// ---------- block-wide min/max reduce helper (256 threads = 4 waves) ----------
__device__ __forceinline__ void block_minmax(float lmn, float lmx, float* red,
                                             float& omn, float& omx){
    #pragma unroll
    for (int off = 32; off > 0; off >>= 1){
        lmn = fminf(lmn, __shfl_xor(lmn, off));
        lmx = fmaxf(lmx, __shfl_xor(lmx, off));
    }
    int wave = threadIdx.x >> 6;
    if ((threadIdx.x & 63) == 0){ red[wave] = lmn; red[4+wave] = lmx; }
    __syncthreads();
    omn = fminf(fminf(red[0], red[1]), fminf(red[2], red[3]));
    omx = fmaxf(fmaxf(red[4], red[5]), fmaxf(red[6], red[7]));
    __syncthreads();
}

// ---------- per-graph normalize (initial importance only) ----------
__global__ __launch_bounds__(256) void k_norm_graph(
    const float* __restrict__ va, const int* __restrict__ gstart,
    float* __restrict__ out)
{
    __shared__ float sv[1024];
    __shared__ float red[8];
    int g = blockIdx.x;
    int s = gstart[g], n = gstart[g+1] - s;
    int tid = threadIdx.x;
    float lmn = 3.4e38f, lmx = -3.4e38f;
    for (int i = tid; i < n; i += 256){
        float v = va[s+i];
        sv[i] = v;
        lmn = fminf(lmn, v); lmx = fmaxf(lmx, v);
    }
    float lo, hi;
    block_minmax(lmn, lmx, red, lo, hi);
    float inv = 1.f/(hi - lo + 1e-8f);
    for (int i = tid; i < n; i += 256) out[s+i] = (sv[i] - lo)*inv;
}

// Fold imp_proj into init_W: W0 is (FT+1) x HD, b0 = init_b + pb @ init_W[FT:]
__global__ void k_fold_init(const float* __restrict__ pW, const float* __restrict__ pb,
                            const float* __restrict__ iW, const float* __restrict__ ib,
                            float* __restrict__ W0, float* __restrict__ b0){
    int j = threadIdx.x;
    for (int k = 0; k < FT; ++k) W0[k*HD + j] = iW[k*HD + j];
    float w2 = 0.f, b2 = 0.f;
    for (int k = 0; k < HD; ++k){
        float w = iW[(FT + k)*HD + j];
        w2 += pW[k]*w;
        b2 += pb[k]*w;
    }
    W0[FT*HD + j] = w2;
    b0[j] = ib[j] + b2;
}

// Wf(256x128) = [uW_top ; msg_W @ uW_bot], bcv = msg_b @ uW_bot.
// grid (257, NLAYERS) x 128.
__global__ void k_fold_layer(const float* __restrict__ msgW, const float* __restrict__ updW,
                             const float* __restrict__ msgb,
                             float* __restrict__ WfA, float* __restrict__ bcvA){
    int l = blockIdx.y;
    const float* mW  = msgW + (size_t)l*HD*HD;
    const float* uW  = updW + (size_t)l*2*HD*HD;
    const float* mb  = msgb + (size_t)l*HD;
    float* Wf  = WfA  + (size_t)l*2*HD*HD;
    float* bcv = bcvA + (size_t)l*HD;
    int j = threadIdx.x;
    int r = blockIdx.x;
    if (r < HD){
        Wf[(size_t)r*HD + j] = uW[(size_t)r*HD + j];
    } else if (r < 2*HD){
        int rr = r - HD;
        const float* uWbot = uW + (size_t)HD*HD;
        float acc = 0.f;
        for (int k = 0; k < HD; ++k)
            acc = fmaf(mW[(size_t)rr*HD + k], uWbot[(size_t)k*HD + j], acc);
        Wf[(size_t)r*HD + j] = acc;
    } else {
        const float* uWbot = uW + (size_t)HD*HD;
        float acc = 0.f;
        for (int k = 0; k < HD; ++k)
            acc = fmaf(mb[k], uWbot[(size_t)k*HD + j], acc);
        bcv[j] = acc;
    }
}

// ---------- init GEMM: h = x @ W0[0:64] + imp*W0[64] + b0 ----------
__global__ __launch_bounds__(256) void k_init(
    const float* __restrict__ x, const float* __restrict__ imp,
    const float* __restrict__ W0, const float* __restrict__ b0v,
    float* __restrict__ h)
{
    __shared__ float lds[MB][FT];
    __shared__ float scs[MB];
    int base = blockIdx.x*MB, tid = threadIdx.x;
    #pragma unroll
    for (int i = 0; i < 2; ++i){
        int fidx = i*256 + tid;
        int t = fidx >> 4, c = fidx & 15;
        float4 v = {0.f,0.f,0.f,0.f};
        if (base + t < NN) v = *(const float4*)&x[(size_t)(base+t)*FT + c*4];
        *(float4*)&lds[t][c*4] = v;
    }
    if (tid < MB) scs[tid] = (base+tid < NN) ? imp[base+tid] : 0.f;
    __syncthreads();

    const int cg = tid & 31, rg = tid >> 5;
    const int c0 = cg*4, r0 = rg*4;
    const float4 wl4 = *(const float4*)&W0[(size_t)FT*HD + c0];
    const float4 b4  = *(const float4*)&b0v[c0];
    float acc[4][4];
    #pragma unroll
    for (int r = 0; r < 4; ++r){
        float s = scs[r0+r];
        acc[r][0] = fmaf(s, wl4.x, b4.x); acc[r][1] = fmaf(s, wl4.y, b4.y);
        acc[r][2] = fmaf(s, wl4.z, b4.z); acc[r][3] = fmaf(s, wl4.w, b4.w);
    }
    #pragma unroll 4
    for (int k4 = 0; k4 < 16; ++k4){
        const float4 w0 = *(const float4*)&W0[(size_t)(k4*4+0)*HD + c0];
        const float4 w1 = *(const float4*)&W0[(size_t)(k4*4+1)*HD + c0];
        const float4 w2 = *(const float4*)&W0[(size_t)(k4*4+2)*HD + c0];
        const float4 w3 = *(const float4*)&W0[(size_t)(k4*4+3)*HD + c0];
        #pragma unroll
        for (int r = 0; r < 4; ++r){
            const float4 a = *(const float4*)&lds[r0+r][k4*4];
            acc[r][0]=fmaf(a.x,w0.x,fmaf(a.y,w1.x,fmaf(a.z,w2.x,fmaf(a.w,w3.x,acc[r][0]))));
            acc[r][1]=fmaf(a.x,w0.y,fmaf(a.y,w1.y,fmaf(a.z,w2.y,fmaf(a.w,w3.y,acc[r][1]))));
            acc[r][2]=fmaf(a.x,w0.z,fmaf(a.y,w1.z,fmaf(a.z,w2.z,fmaf(a.w,w3.z,acc[r][2]))));
            acc[r][3]=fmaf(a.x,w0.w,fmaf(a.y,w1.w,fmaf(a.z,w2.w,fmaf(a.w,w3.w,acc[r][3]))));
        }
    }
    #pragma unroll
    for (int r = 0; r < 4; ++r)
        if (base + r0 + r < NN)
            *(float4*)&h[(size_t)(base+r0+r)*HD + c0] =
                make_float4(acc[r][0], acc[r][1], acc[r][2], acc[r][3]);
}

// ---------- per-layer mega kernel: fused gather + conv + gate ----------
// Gather each node's in-edge sum of h[src] directly into LDS (was k_aggregate),
// then the round-5 GEMM body (measured-best: VGPR 52, zero spill).
__global__ __launch_bounds__(256, 3) void k_layer(
    const float* __restrict__ h,
    const int* __restrict__ rowst, const int* __restrict__ csr,
    const float* __restrict__ imp,
    const float* __restrict__ Wf, const float* __restrict__ bcv,
    const float* __restrict__ ub,
    const float* __restrict__ gW, const float* __restrict__ gb,
    const float* __restrict__ prW, const float* __restrict__ prb,
    float* __restrict__ outbuf, float* __restrict__ ta)
{
    __shared__ float lds[MB][256];   // cols 0..127: h ; 128..255: aggr, then conv
    __shared__ float scs[MB];
    __shared__ float dgs[MB];
    __shared__ float red[8][4];
    const int base = blockIdx.x*MB, tid = threadIdx.x;

    // stage h tile (cols 0..127): 1024 float4, 4 per thread
    #pragma unroll
    for (int i = 0; i < 4; ++i){
        int fidx = i*256 + tid;
        int t = fidx >> 5, c = fidx & 31;
        float4 v = {0.f,0.f,0.f,0.f};
        if (base + t < NN) v = *(const float4*)&h[(size_t)(base+t)*HD + c*4];
        *(float4*)&lds[t][c*4] = v;
    }
    if (tid < MB) scs[tid] = (base+tid < NN) ? imp[base+tid] : 0.f;

    // fused gather into cols 128..255: 4 passes x 8 nodes, 32 lanes/node
    {
        const int lane = tid & 31;
        #pragma unroll
        for (int pass = 0; pass < 4; ++pass){
            const int t = pass*8 + (tid >> 5);
            const int node = base + t;
            float4 a0 = {0.f,0.f,0.f,0.f}, a1 = a0, a2 = a0, a3 = a0;
            float4 a4 = a0, a5 = a0, a6 = a0, a7 = a0;
            if (node < NN){
                int e0 = rowst[node], e1 = rowst[node+1];
                if (lane == 0) dgs[t] = (float)(e1 - e0);
                int e = e0;
                for (; e + 7 < e1; e += 8){
                    int s0 = csr[e],   s1 = csr[e+1], s2 = csr[e+2], s3 = csr[e+3];
                    int s4 = csr[e+4], s5 = csr[e+5], s6 = csr[e+6], s7 = csr[e+7];
                    const float4 v0 = *(const float4*)&h[(size_t)s0*HD + lane*4];
                    const float4 v1 = *(const float4*)&h[(size_t)s1*HD + lane*4];
                    const float4 v2 = *(const float4*)&h[(size_t)s2*HD + lane*4];
                    const float4 v3 = *(const float4*)&h[(size_t)s3*HD + lane*4];
                    const float4 v4 = *(const float4*)&h[(size_t)s4*HD + lane*4];
                    const float4 v5 = *(const float4*)&h[(size_t)s5*HD + lane*4];
                    const float4 v6 = *(const float4*)&h[(size_t)s6*HD + lane*4];
                    const float4 v7 = *(const float4*)&h[(size_t)s7*HD + lane*4];
                    a0.x += v0.x; a0.y += v0.y; a0.z += v0.z; a0.w += v0.w;
                    a1.x += v1.x; a1.y += v1.y; a1.z += v1.z; a1.w += v1.w;
                    a2.x += v2.x; a2.y += v2.y; a2.z += v2.z; a2.w += v2.w;
                    a3.x += v3.x; a3.y += v3.y; a3.z += v3.z; a3.w += v3.w;
                    a4.x += v4.x; a4.y += v4.y; a4.z += v4.z; a4.w += v4.w;
                    a5.x += v5.x; a5.y += v5.y; a5.z += v5.z; a5.w += v5.w;
                    a6.x += v6.x; a6.y += v6.y; a6.z += v6.z; a6.w += v6.w;
                    a7.x += v7.x; a7.y += v7.y; a7.z += v7.z; a7.w += v7.w;
                }
                for (; e + 3 < e1; e += 4){
                    int s0 = csr[e], s1 = csr[e+1], s2 = csr[e+2], s3 = csr[e+3];
                    const float4 v0 = *(const float4*)&h[(size_t)s0*HD + lane*4];
                    const float4 v1 = *(const float4*)&h[(size_t)s1*HD + lane*4];
                    const float4 v2 = *(const float4*)&h[(size_t)s2*HD + lane*4];
                    const float4 v3 = *(const float4*)&h[(size_t)s3*HD + lane*4];
                    a0.x += v0.x; a0.y += v0.y; a0.z += v0.z; a0.w += v0.w;
                    a1.x += v1.x; a1.y += v1.y; a1.z += v1.z; a1.w += v1.w;
                    a2.x += v2.x; a2.y += v2.y; a2.z += v2.z; a2.w += v2.w;
                    a3.x += v3.x; a3.y += v3.y; a3.z += v3.z; a3.w += v3.w;
                }
                for (; e < e1; ++e){
                    int s0 = csr[e];
                    const float4 v0 = *(const float4*)&h[(size_t)s0*HD + lane*4];
                    a0.x += v0.x; a0.y += v0.y; a0.z += v0.z; a0.w += v0.w;
                }
            } else if (lane == 0) dgs[t] = 0.f;
            a0.x += a1.x; a0.y += a1.y; a0.z += a1.z; a0.w += a1.w;
            a2.x += a3.x; a2.y += a3.y; a2.z += a3.z; a2.w += a3.w;
            a4.x += a5.x; a4.y += a5.y; a4.z += a5.z; a4.w += a5.w;
            a6.x += a7.x; a6.y += a7.y; a6.z += a7.z; a6.w += a7.w;
            a0.x += a2.x; a0.y += a2.y; a0.z += a2.z; a0.w += a2.w;
            a4.x += a6.x; a4.y += a6.y; a4.z += a6.z; a4.w += a6.w;
            a0.x += a4.x; a0.y += a4.y; a0.z += a4.z; a0.w += a4.w;
            *(float4*)&lds[t][HD + lane*4] = a0;
        }
    }
    __syncthreads();

    const int cg = tid & 31, rg = tid >> 5;
    const int c0 = cg*4, r0 = rg*4;

    // conv = [h|aggr] @ Wf + deg*bc + ub
    const float4 bc4 = *(const float4*)&bcv[c0];
    const float4 ub4 = *(const float4*)&ub[c0];
    float acc[4][4];
    #pragma unroll
    for (int r = 0; r < 4; ++r){
        float d = dgs[r0+r];
        acc[r][0] = fmaf(d, bc4.x, ub4.x); acc[r][1] = fmaf(d, bc4.y, ub4.y);
        acc[r][2] = fmaf(d, bc4.z, ub4.z); acc[r][3] = fmaf(d, bc4.w, ub4.w);
    }
    #pragma unroll 4
    for (int k4 = 0; k4 < 64; ++k4){
        const float4 w0 = *(const float4*)&Wf[(size_t)(k4*4+0)*HD + c0];
        const float4 w1 = *(const float4*)&Wf[(size_t)(k4*4+1)*HD + c0];
        const float4 w2 = *(const float4*)&Wf[(size_t)(k4*4+2)*HD + c0];
        const float4 w3 = *(const float4*)&Wf[(size_t)(k4*4+3)*HD + c0];
        #pragma unroll
        for (int r = 0; r < 4; ++r){
            const float4 a = *(const float4*)&lds[r0+r][k4*4];
            acc[r][0]=fmaf(a.x,w0.x,fmaf(a.y,w1.x,fmaf(a.z,w2.x,fmaf(a.w,w3.x,acc[r][0]))));
            acc[r][1]=fmaf(a.x,w0.y,fmaf(a.y,w1.y,fmaf(a.z,w2.y,fmaf(a.w,w3.y,acc[r][1]))));
            acc[r][2]=fmaf(a.x,w0.z,fmaf(a.y,w1.z,fmaf(a.z,w2.z,fmaf(a.w,w3.z,acc[r][2]))));
            acc[r][3]=fmaf(a.x,w0.w,fmaf(a.y,w1.w,fmaf(a.z,w2.w,fmaf(a.w,w3.w,acc[r][3]))));
        }
    }
    __syncthreads();   // all conv-GEMM reads of the aggr half are done
    #pragma unroll
    for (int r = 0; r < 4; ++r)
        *(float4*)&lds[r0+r][HD + c0] = make_float4(acc[r][0],acc[r][1],acc[r][2],acc[r][3]);
    __syncthreads();

    // gate z = conv@gW_top + imp*gW[128] + gb   (conv now in lds cols 128..255)
    const float4 gwl = *(const float4*)&gW[(size_t)HD*HD + c0];
    const float4 gb4 = *(const float4*)&gb[c0];
    float z[4][4];
    #pragma unroll
    for (int r = 0; r < 4; ++r){
        float s = scs[r0+r];
        z[r][0] = fmaf(s, gwl.x, gb4.x); z[r][1] = fmaf(s, gwl.y, gb4.y);
        z[r][2] = fmaf(s, gwl.z, gb4.z); z[r][3] = fmaf(s, gwl.w, gb4.w);
    }
    #pragma unroll 4
    for (int k4 = 0; k4 < 32; ++k4){
        const float4 w0 = *(const float4*)&gW[(size_t)(k4*4+0)*HD + c0];
        const float4 w1 = *(const float4*)&gW[(size_t)(k4*4+1)*HD + c0];
        const float4 w2 = *(const float4*)&gW[(size_t)(k4*4+2)*HD + c0];
        const float4 w3 = *(const float4*)&gW[(size_t)(k4*4+3)*HD + c0];
        #pragma unroll
        for (int r = 0; r < 4; ++r){
            const float4 a = *(const float4*)&lds[r0+r][HD + k4*4];
            z[r][0]=fmaf(a.x,w0.x,fmaf(a.y,w1.x,fmaf(a.z,w2.x,fmaf(a.w,w3.x,z[r][0]))));
            z[r][1]=fmaf(a.x,w0.y,fmaf(a.y,w1.y,fmaf(a.z,w2.y,fmaf(a.w,w3.y,z[r][1]))));
            z[r][2]=fmaf(a.x,w0.z,fmaf(a.y,w1.z,fmaf(a.z,w2.z,fmaf(a.w,w3.z,z[r][2]))));
            z[r][3]=fmaf(a.x,w0.w,fmaf(a.y,w1.w,fmaf(a.z,w2.w,fmaf(a.w,w3.w,z[r][3]))));
        }
    }

    // epilogue: gate mix, store out, prop partials (conv still in acc regs)
    const float4 pr4 = *(const float4*)&prW[c0];
    float psum[4];
    #pragma unroll
    for (int r = 0; r < 4; ++r){
        const float4 hv = *(const float4*)&lds[r0+r][c0];
        float g0 = 1.f/(1.f + expf(-z[r][0]));
        float g1 = 1.f/(1.f + expf(-z[r][1]));
        float g2 = 1.f/(1.f + expf(-z[r][2]));
        float g3 = 1.f/(1.f + expf(-z[r][3]));
        float o0 = g0*acc[r][0] + (1.f-g0)*hv.x;
        float o1 = g1*acc[r][1] + (1.f-g1)*hv.y;
        float o2 = g2*acc[r][2] + (1.f-g2)*hv.z;
        float o3 = g3*acc[r][3] + (1.f-g3)*hv.w;
        if (base + r0 + r < NN)
            *(float4*)&outbuf[(size_t)(base+r0+r)*HD + c0] = make_float4(o0,o1,o2,o3);
        psum[r] = o0*pr4.x + o1*pr4.y + o2*pr4.z + o3*pr4.w;
    }
    #pragma unroll
    for (int r = 0; r < 4; ++r){
        float v = psum[r];
        #pragma unroll
        for (int off = 16; off > 0; off >>= 1) v += __shfl_xor(v, off);
        if (cg == 0) red[rg][r] = v;
    }
    __syncthreads();
    if (tid < MB && base + tid < NN)
        ta[base+tid] = 0.9f*scs[tid] + 0.1f*(red[tid>>2][tid&3] + prb[0]);
}

// ---------- CSR build (by dst) ----------
__global__ void k_deg(const int* __restrict__ dst, int* deg){
    int e = blockIdx.x*blockDim.x + threadIdx.x;
    if (e < NE) atomicAdd(&deg[dst[e]], 1);
}

__global__ __launch_bounds__(1024) void k_scan(const int* __restrict__ deg,
                                               int* __restrict__ rowstart){
    __shared__ int wtot[16];
    __shared__ int woff[16];
    __shared__ int carry;
    int tid = threadIdx.x, lane = tid & 63, wv = tid >> 6;
    if (tid == 0) carry = 0;
    __syncthreads();
    for (int base = 0; base < NN; base += 1024){
        int i = base + tid;
        int v = (i < NN) ? deg[i] : 0;
        int x = v;
        #pragma unroll
        for (int off = 1; off < 64; off <<= 1){
            int y = __shfl_up(x, off);
            if (lane >= off) x += y;
        }
        if (lane == 63) wtot[wv] = x;
        __syncthreads();
        if (tid == 0){
            int a = carry;
            for (int w2 = 0; w2 < 16; ++w2){ woff[w2] = a; a += wtot[w2]; }
            carry = a;
        }
        __syncthreads();
        if (i < NN) rowstart[i] = woff[wv] + x - v;   // exclusive
    }
    __syncthreads();
    if (tid == 0) rowstart[NN] = carry;
}

__global__ void k_copy_int(const int* __restrict__ a, int* __restrict__ b, int n){
    int i = blockIdx.x*blockDim.x + threadIdx.x;
    if (i < n) b[i] = a[i];
}

__global__ void k_fill(const int* __restrict__ src, const int* __restrict__ dst,
                       int* cursor, int* __restrict__ csr){
    int e = blockIdx.x*blockDim.x + threadIdx.x;
    if (e < NE){
        int d = dst[e];
        int p = atomicAdd(&cursor[d], 1);
        csr[p] = src[e];
    }
}

// ---------- fused graph-norm (4 col-slices per graph) + importance chain ----
__global__ __launch_bounds__(256) void k_gnorm(
    const float* __restrict__ v, const int* __restrict__ gstart,
    const float* __restrict__ nw, const float* __restrict__ nb,
    const float* __restrict__ na, float* __restrict__ hout,
    const float* __restrict__ tsrc, float* __restrict__ tdst)
{
    int g = blockIdx.x;
    int part = blockIdx.y;
    int s = gstart[g], n = gstart[g+1] - s;
    int tid = threadIdx.x;

    if (part == 4){
        __shared__ float sv[1024];
        __shared__ float red[8];
        float lmn = 3.4e38f, lmx = -3.4e38f;
        for (int i = tid; i < n; i += 256){
            float val = tsrc[s+i]; sv[i] = val;
            lmn = fminf(lmn, val); lmx = fmaxf(lmx, val);
        }
        float lo, hi;
        block_minmax(lmn, lmx, red, lo, hi);
        float inv = 1.f/(hi - lo + 1e-8f);
        lmn = 3.4e38f; lmx = -3.4e38f;
        for (int i = tid; i < n; i += 256){
            float t2 = (sv[i] - lo)*inv;
            if (t2 < 0.1f) t2 = 0.f;
            sv[i] = t2;
            lmn = fminf(lmn, t2); lmx = fmaxf(lmx, t2);
        }
        float lo2, hi2;
        block_minmax(lmn, lmx, red, lo2, hi2);
        float inv2 = 1.f/(hi2 - lo2 + 1e-8f);
        for (int i = tid; i < n; i += 256) tdst[s+i] = (sv[i] - lo2)*inv2;
        return;
    }

    __shared__ float4 rs1[32][8];
    __shared__ float4 rs2[32][8];
    __shared__ float amv[32], scv[32], nbv[32];
    int rg = tid >> 3, c4l = tid & 7;
    size_t coff = (size_t)part*32 + c4l*4;
    float4 s1 = {0.f,0.f,0.f,0.f}, s2 = {0.f,0.f,0.f,0.f};
    for (int i = rg; i < n; i += 32){
        const float4 vv = *(const float4*)&v[(size_t)(s+i)*HD + coff];
        s1.x += vv.x; s1.y += vv.y; s1.z += vv.z; s1.w += vv.w;
        s2.x += vv.x*vv.x; s2.y += vv.y*vv.y; s2.z += vv.z*vv.z; s2.w += vv.w*vv.w;
    }
    rs1[rg][c4l] = s1; rs2[rg][c4l] = s2;
    __syncthreads();
    if (tid < 8){
        float4 t1 = {0.f,0.f,0.f,0.f}, t2 = {0.f,0.f,0.f,0.f};
        for (int r = 0; r < 32; ++r){
            float4 a = rs1[r][tid]; float4 b = rs2[r][tid];
            t1.x += a.x; t1.y += a.y; t1.z += a.z; t1.w += a.w;
            t2.x += b.x; t2.y += b.y; t2.z += b.z; t2.w += b.w;
        }
        float fn = (float)n;
        float S1[4] = {t1.x,t1.y,t1.z,t1.w};
        float S2[4] = {t2.x,t2.y,t2.z,t2.w};
        #pragma unroll
        for (int e = 0; e < 4; ++e){
            int j = part*32 + tid*4 + e;
            float m = S1[e]/fn;
            float aj = na[j];
            float var = S2[e]/fn - (2.f*aj - aj*aj)*m*m;
            float stdv = sqrtf(var + 1e-5f);
            amv[tid*4+e] = aj*m;
            scv[tid*4+e] = nw[j]/stdv;
            nbv[tid*4+e] = nb[j];
        }
    }
    __syncthreads();
    const float4 am4 = *(const float4*)&amv[c4l*4];
    const float4 sc4 = *(const float4*)&scv[c4l*4];
    const float4 nb4 = *(const float4*)&nbv[c4l*4];
    for (int i = rg; i < n; i += 32){
        const float4 vv = *(const float4*)&v[(size_t)(s+i)*HD + coff];
        float4 r;
        r.x = fmaxf((vv.x - am4.x)*sc4.x + nb4.x, 0.f);
        r.y = fmaxf((vv.y - am4.y)*sc4.y + nb4.y, 0.f);
        r.z = fmaxf((vv.z - am4.z)*sc4.z + nb4.z, 0.f);
        r.w = fmaxf((vv.w - am4.w)*sc4.w + nb4.w, 0.f);
        *(float4*)&hout[(size_t)(s+i)*HD + coff] = r;
    }
}

// ---------- fused final: column-sum + logits GEMM + final importance --------
__global__ __launch_bounds__(1024) void k_logits(
    const float* __restrict__ h, const int* __restrict__ gstart,
    const float* __restrict__ fW, const float* __restrict__ fb,
    const float* __restrict__ imp0, const float* __restrict__ impf,
    float* __restrict__ outp)
{
    __shared__ float4 rs1[32][32];
    __shared__ float gsum[HD];
    __shared__ float redn[32];
    int g = blockIdx.x;
    int s = gstart[g], n = gstart[g+1] - s;
    int tid = threadIdx.x;
    int c4 = tid & 31, rg = tid >> 5;
    float4 s1 = {0.f,0.f,0.f,0.f};
    for (int i = rg; i < n; i += 32){
        const float4 vv = *(const float4*)&h[(size_t)(s+i)*HD + c4*4];
        s1.x += vv.x; s1.y += vv.y; s1.z += vv.z; s1.w += vv.w;
    }
    rs1[rg][c4] = s1;
    __syncthreads();
    if (tid < 32){
        float4 t1 = {0.f,0.f,0.f,0.f};
        for (int r = 0; r < 32; ++r){
            float4 a = rs1[r][tid];
            t1.x += a.x; t1.y += a.y; t1.z += a.z; t1.w += a.w;
        }
        gsum[tid*4+0] = t1.x; gsum[tid*4+1] = t1.y;
        gsum[tid*4+2] = t1.z; gsum[tid*4+3] = t1.w;
    }
    __syncthreads();
    if (tid < 32){
        int o = tid;
        float acc = 0.f;
        for (int k = 0; k < HD; ++k) acc = fmaf(gsum[k], fW[k*32 + o], acc);
        outp[g*32 + o] = acc/(float)n + fb[o];
    }
    float val = 0.f;
    bool has = (tid < n);
    float lmn = 3.4e38f, lmx = -3.4e38f;
    if (has){ val = imp0[s+tid] + impf[s+tid]; lmn = val; lmx = val; }
    #pragma unroll
    for (int off = 32; off > 0; off >>= 1){
        lmn = fminf(lmn, __shfl_xor(lmn, off));
        lmx = fmaxf(lmx, __shfl_xor(lmx, off));
    }
    int wv = tid >> 6, lane = tid & 63;
    if (lane == 0){ redn[wv] = lmn; redn[16+wv] = lmx; }
    __syncthreads();
    float lo = redn[0], hi = redn[16];
    for (int r2 = 1; r2 < 16; ++r2){
        lo = fminf(lo, redn[r2]); hi = fmaxf(hi, redn[16+r2]);
    }
    if (has) outp[NG*32 + s + tid] = (val - lo)/(hi - lo + 1e-8f);
}

extern "C" void kernel_launch(void* const* d_in, const int* in_sizes, int n_in,
                              void* d_out, int out_size, void* d_ws, size_t ws_size,
                              hipStream_t stream){
    const float* x    = (const float*)d_in[0];
    const float* imp0 = (const float*)d_in[2];
    const float* pW   = (const float*)d_in[3];
    const float* pb   = (const float*)d_in[4];
    const float* iW   = (const float*)d_in[5];
    const float* ib   = (const float*)d_in[6];
    const float* msgW = (const float*)d_in[7];
    const float* msgb = (const float*)d_in[8];
    const float* updW = (const float*)d_in[9];
    const float* updb = (const float*)d_in[10];
    const float* gWt  = (const float*)d_in[11];
    const float* gb   = (const float*)d_in[12];
    const float* prW  = (const float*)d_in[13];
    const float* prb  = (const float*)d_in[14];
    const float* nw   = (const float*)d_in[15];
    const float* nb   = (const float*)d_in[16];
    const float* na   = (const float*)d_in[17];
    const float* fW   = (const float*)d_in[18];
    const float* fb   = (const float*)d_in[19];
    const int* eidx   = (const int*)d_in[20];
    const int* batch  = (const int*)d_in[21];
    const int* esrc = eidx;
    const int* edst = eidx + NE;
    float* outp = (float*)d_out;

    char* w = (char*)d_ws;
    size_t off = 0;
    auto alloc = [&](size_t bytes)->char*{
        char* p = w + off;
        off += (bytes + 255) & ~(size_t)255;
        return p;
    };
    float* h     = (float*)alloc((size_t)NN*HD*4);
    float* outA  = (float*)alloc((size_t)NN*HD*4);
    float* ta    = (float*)alloc((size_t)NN*4);
    float* imp   = (float*)alloc((size_t)NN*4);
    float* W0    = (float*)alloc((size_t)(FT+1)*HD*4);
    float* b0    = (float*)alloc((size_t)HD*4);
    float* Wf    = (float*)alloc((size_t)NLAYERS*2*HD*HD*4);
    float* bcv   = (float*)alloc((size_t)NLAYERS*HD*4);
    int* gstart  = (int*)alloc((size_t)(NG+1)*4);
    int* deg     = (int*)alloc((size_t)NN*4);
    int* rowst   = (int*)alloc((size_t)(NN+1)*4);
    int* cursor  = (int*)alloc((size_t)NN*4);
    int* csr     = (int*)alloc((size_t)NE*4);

    // graph boundaries
    k_gbounds<<<196, 256, 0, stream>>>(batch, gstart);

    // CSR by dst
    hipMemsetAsync(deg, 0, NN*4, stream);
    k_deg<<<3125, 256, 0, stream>>>(edst, deg);
    k_scan<<<1, 1024, 0, stream>>>(deg, rowst);
    k_copy_int<<<196, 256, 0, stream>>>(rowst, cursor, NN);
    k_fill<<<3125, 256, 0, stream>>>(esrc, edst, cursor, csr);

    // weight folds
    k_fold_init<<<1, 128, 0, stream>>>(pW, pb, iW, ib, W0, b0);
    k_fold_layer<<<dim3(257, NLAYERS), 128, 0, stream>>>(msgW, updW, msgb, Wf, bcv);

    // importance = normalize(imp0); h = init GEMM
    k_norm_graph<<<NG, 256, 0, stream>>>(imp0, gstart, imp);
    k_init<<<NBLK, 256, 0, stream>>>(x, imp, W0, b0, h);

    for (int l = 0; l < NLAYERS; ++l){
        k_layer<<<NBLK, 256, 0, stream>>>(
            h, rowst, csr, imp,
            Wf + (size_t)l*2*HD*HD, bcv + (size_t)l*HD,
            updb + (size_t)l*HD, gWt + (size_t)l*(HD+1)*HD, gb + (size_t)l*HD,
            prW + (size_t)l*HD, prb + l, outA, ta);
        k_gnorm<<<dim3(NG,5), 256, 0, stream>>>(outA, gstart,
            nw + (size_t)l*HD, nb + (size_t)l*HD, na + (size_t)l*HD, h, ta, imp);
    }

    // logits + final importance
    k_logits<<<NG, 1024, 0, stream>>>(h, gstart, fW, fb, imp0, imp, outp);
}

// Round 11
// 688.045 us; speedup vs baseline: 1.2936x; 1.0022x over previous
//
#include <hip/hip_runtime.h>
#include <cstdint>

#define NN 50000
#define NE 800000
#define NG 64
#define HD 128
#define FT 64
#define NLAYERS 3
#define MB 32
#define NBLK 1563   // ceil(NN/MB)

// ---------- graph boundaries (batch is sorted contiguous runs) ----------
__global__ void k_gbounds(const int* __restrict__ batch, int* __restrict__ gstart){
    int i = blockIdx.x*blockDim.x + threadIdx.x;
    if (i >= NN) return;
    int g = batch[i];
    if (i == 0){ for (int q = 0; q <= g; ++q) gstart[q] = 0; }
    else { int gp = batch[i-1]; for (int q = gp+1; q <= g; ++q) gstart[q] = i; }
    if (i == NN-1){ for (int q = g+1; q <= NG; ++q) gstart[q] = NN; }
}

// ---------- block-wide min/max reduce helper (256 threads = 4 waves) ----------
__device__ __forceinline__ void block_minmax(float lmn, float lmx, float* red,
                                             float& omn, float& omx){
    #pragma unroll
    for (int off = 32; off > 0; off >>= 1){
        lmn = fminf(lmn, __shfl_xor(lmn, off));
        lmx = fmaxf(lmx, __shfl_xor(lmx, off));
    }
    int wave = threadIdx.x >> 6;
    if ((threadIdx.x & 63) == 0){ red[wave] = lmn; red[4+wave] = lmx; }
    __syncthreads();
    omn = fminf(fminf(red[0], red[1]), fminf(red[2], red[3]));
    omx = fmaxf(fmaxf(red[4], red[5]), fmaxf(red[6], red[7]));
    __syncthreads();
}

// ---------- per-graph normalize (initial importance only) ----------
__global__ __launch_bounds__(256) void k_norm_graph(
    const float* __restrict__ va, const int* __restrict__ gstart,
    float* __restrict__ out)
{
    __shared__ float sv[1024];
    __shared__ float red[8];
    int g = blockIdx.x;
    int s = gstart[g], n = gstart[g+1] - s;
    int tid = threadIdx.x;
    float lmn = 3.4e38f, lmx = -3.4e38f;
    for (int i = tid; i < n; i += 256){
        float v = va[s+i];
        sv[i] = v;
        lmn = fminf(lmn, v); lmx = fmaxf(lmx, v);
    }
    float lo, hi;
    block_minmax(lmn, lmx, red, lo, hi);
    float inv = 1.f/(hi - lo + 1e-8f);
    for (int i = tid; i < n; i += 256) out[s+i] = (sv[i] - lo)*inv;
}

// Fold imp_proj into init_W: W0 is (FT+1) x HD, b0 = init_b + pb @ init_W[FT:]
__global__ void k_fold_init(const float* __restrict__ pW, const float* __restrict__ pb,
                            const float* __restrict__ iW, const float* __restrict__ ib,
                            float* __restrict__ W0, float* __restrict__ b0){
    int j = threadIdx.x;
    for (int k = 0; k < FT; ++k) W0[k*HD + j] = iW[k*HD + j];
    float w2 = 0.f, b2 = 0.f;
    for (int k = 0; k < HD; ++k){
        float w = iW[(FT + k)*HD + j];
        w2 += pW[k]*w;
        b2 += pb[k]*w;
    }
    W0[FT*HD + j] = w2;
    b0[j] = ib[j] + b2;
}

// Wf(256x128) = [uW_top ; msg_W @ uW_bot], bcv = msg_b @ uW_bot.
// grid (257, NLAYERS) x 128.
__global__ void k_fold_layer(const float* __restrict__ msgW, const float* __restrict__ updW,
                             const float* __restrict__ msgb,
                             float* __restrict__ WfA, float* __restrict__ bcvA){
    int l = blockIdx.y;
    const float* mW  = msgW + (size_t)l*HD*HD;
    const float* uW  = updW + (size_t)l*2*HD*HD;
    const float* mb  = msgb + (size_t)l*HD;
    float* Wf  = WfA  + (size_t)l*2*HD*HD;
    float* bcv = bcvA + (size_t)l*HD;
    int j = threadIdx.x;
    int r = blockIdx.x;
    if (r < HD){
        Wf[(size_t)r*HD + j] = uW[(size_t)r*HD + j];
    } else if (r < 2*HD){
        int rr = r - HD;
        const float* uWbot = uW + (size_t)HD*HD;
        float acc = 0.f;
        for (int k = 0; k < HD; ++k)
            acc = fmaf(mW[(size_t)rr*HD + k], uWbot[(size_t)k*HD + j], acc);
        Wf[(size_t)r*HD + j] = acc;
    } else {
        const float* uWbot = uW + (size_t)HD*HD;
        float acc = 0.f;
        for (int k = 0; k < HD; ++k)
            acc = fmaf(mb[k], uWbot[(size_t)k*HD + j], acc);
        bcv[j] = acc;
    }
}

// ---------- init GEMM: h = x @ W0[0:64] + imp*W0[64] + b0 ----------
__global__ __launch_bounds__(256) void k_init(
    const float* __restrict__ x, const float* __restrict__ imp,
    const float* __restrict__ W0, const float* __restrict__ b0v,
    float* __restrict__ h)
{
    __shared__ float lds[MB][FT];
    __shared__ float scs[MB];
    int base = blockIdx.x*MB, tid = threadIdx.x;
    #pragma unroll
    for (int i = 0; i < 2; ++i){
        int fidx = i*256 + tid;
        int t = fidx >> 4, c = fidx & 15;
        float4 v = {0.f,0.f,0.f,0.f};
        if (base + t < NN) v = *(const float4*)&x[(size_t)(base+t)*FT + c*4];
        *(float4*)&lds[t][c*4] = v;
    }
    if (tid < MB) scs[tid] = (base+tid < NN) ? imp[base+tid] : 0.f;
    __syncthreads();

    const int cg = tid & 31, rg = tid >> 5;
    const int c0 = cg*4, r0 = rg*4;
    const float4 wl4 = *(const float4*)&W0[(size_t)FT*HD + c0];
    const float4 b4  = *(const float4*)&b0v[c0];
    float acc[4][4];
    #pragma unroll
    for (int r = 0; r < 4; ++r){
        float s = scs[r0+r];
        acc[r][0] = fmaf(s, wl4.x, b4.x); acc[r][1] = fmaf(s, wl4.y, b4.y);
        acc[r][2] = fmaf(s, wl4.z, b4.z); acc[r][3] = fmaf(s, wl4.w, b4.w);
    }
    #pragma unroll 4
    for (int k4 = 0; k4 < 16; ++k4){
        const float4 w0 = *(const float4*)&W0[(size_t)(k4*4+0)*HD + c0];
        const float4 w1 = *(const float4*)&W0[(size_t)(k4*4+1)*HD + c0];
        const float4 w2 = *(const float4*)&W0[(size_t)(k4*4+2)*HD + c0];
        const float4 w3 = *(const float4*)&W0[(size_t)(k4*4+3)*HD + c0];
        #pragma unroll
        for (int r = 0; r < 4; ++r){
            const float4 a = *(const float4*)&lds[r0+r][k4*4];
            acc[r][0]=fmaf(a.x,w0.x,fmaf(a.y,w1.x,fmaf(a.z,w2.x,fmaf(a.w,w3.x,acc[r][0]))));
            acc[r][1]=fmaf(a.x,w0.y,fmaf(a.y,w1.y,fmaf(a.z,w2.y,fmaf(a.w,w3.y,acc[r][1]))));
            acc[r][2]=fmaf(a.x,w0.z,fmaf(a.y,w1.z,fmaf(a.z,w2.z,fmaf(a.w,w3.z,acc[r][2]))));
            acc[r][3]=fmaf(a.x,w0.w,fmaf(a.y,w1.w,fmaf(a.z,w2.w,fmaf(a.w,w3.w,acc[r][3]))));
        }
    }
    #pragma unroll
    for (int r = 0; r < 4; ++r)
        if (base + r0 + r < NN)
            *(float4*)&h[(size_t)(base+r0+r)*HD + c0] =
                make_float4(acc[r][0], acc[r][1], acc[r][2], acc[r][3]);
}

// ---------- per-layer mega kernel: fused gather + conv + gate ----------
// Round-10 structure; occupancy raised to 4 blocks/CU (LDS 33.3KB x4 = 133KB,
// VGPR 52 -> fits). Both the latency-bound gather and the load-bound GEMM
// gain concurrency.
__global__ __launch_bounds__(256, 4) void k_layer(
    const float* __restrict__ h,
    const int* __restrict__ rowst, const int* __restrict__ csr,
    const float* __restrict__ imp,
    const float* __restrict__ Wf, const float* __restrict__ bcv,
    const float* __restrict__ ub,
    const float* __restrict__ gW, const float* __restrict__ gb,
    const float* __restrict__ prW, const float* __restrict__ prb,
    float* __restrict__ outbuf, float* __restrict__ ta)
{
    __shared__ float lds[MB][256];   // cols 0..127: h ; 128..255: aggr, then conv
    __shared__ float scs[MB];
    __shared__ float dgs[MB];
    __shared__ float red[8][4];
    const int base = blockIdx.x*MB, tid = threadIdx.x;

    // stage h tile (cols 0..127): 1024 float4, 4 per thread
    #pragma unroll
    for (int i = 0; i < 4; ++i){
        int fidx = i*256 + tid;
        int t = fidx >> 5, c = fidx & 31;
        float4 v = {0.f,0.f,0.f,0.f};
        if (base + t < NN) v = *(const float4*)&h[(size_t)(base+t)*HD + c*4];
        *(float4*)&lds[t][c*4] = v;
    }
    if (tid < MB) scs[tid] = (base+tid < NN) ? imp[base+tid] : 0.f;

    // fused gather into cols 128..255: 4 passes x 8 nodes, 32 lanes/node
    {
        const int lane = tid & 31;
        #pragma unroll
        for (int pass = 0; pass < 4; ++pass){
            const int t = pass*8 + (tid >> 5);
            const int node = base + t;
            float4 a0 = {0.f,0.f,0.f,0.f}, a1 = a0, a2 = a0, a3 = a0;
            float4 a4 = a0, a5 = a0, a6 = a0, a7 = a0;
            if (node < NN){
                int e0 = rowst[node], e1 = rowst[node+1];
                if (lane == 0) dgs[t] = (float)(e1 - e0);
                int e = e0;
                for (; e + 7 < e1; e += 8){
                    int s0 = csr[e],   s1 = csr[e+1], s2 = csr[e+2], s3 = csr[e+3];
                    int s4 = csr[e+4], s5 = csr[e+5], s6 = csr[e+6], s7 = csr[e+7];
                    const float4 v0 = *(const float4*)&h[(size_t)s0*HD + lane*4];
                    const float4 v1 = *(const float4*)&h[(size_t)s1*HD + lane*4];
                    const float4 v2 = *(const float4*)&h[(size_t)s2*HD + lane*4];
                    const float4 v3 = *(const float4*)&h[(size_t)s3*HD + lane*4];
                    const float4 v4 = *(const float4*)&h[(size_t)s4*HD + lane*4];
                    const float4 v5 = *(const float4*)&h[(size_t)s5*HD + lane*4];
                    const float4 v6 = *(const float4*)&h[(size_t)s6*HD + lane*4];
                    const float4 v7 = *(const float4*)&h[(size_t)s7*HD + lane*4];
                    a0.x += v0.x; a0.y += v0.y; a0.z += v0.z; a0.w += v0.w;
                    a1.x += v1.x; a1.y += v1.y; a1.z += v1.z; a1.w += v1.w;
                    a2.x += v2.x; a2.y += v2.y; a2.z += v2.z; a2.w += v2.w;
                    a3.x += v3.x; a3.y += v3.y; a3.z += v3.z; a3.w += v3.w;
                    a4.x += v4.x; a4.y += v4.y; a4.z += v4.z; a4.w += v4.w;
                    a5.x += v5.x; a5.y += v5.y; a5.z += v5.z; a5.w += v5.w;
                    a6.x += v6.x; a6.y += v6.y; a6.z += v6.z; a6.w += v6.w;
                    a7.x += v7.x; a7.y += v7.y; a7.z += v7.z; a7.w += v7.w;
                }
                for (; e + 3 < e1; e += 4){
                    int s0 = csr[e], s1 = csr[e+1], s2 = csr[e+2], s3 = csr[e+3];
                    const float4 v0 = *(const float4*)&h[(size_t)s0*HD + lane*4];
                    const float4 v1 = *(const float4*)&h[(size_t)s1*HD + lane*4];
                    const float4 v2 = *(const float4*)&h[(size_t)s2*HD + lane*4];
                    const float4 v3 = *(const float4*)&h[(size_t)s3*HD + lane*4];
                    a0.x += v0.x; a0.y += v0.y; a0.z += v0.z; a0.w += v0.w;
                    a1.x += v1.x; a1.y += v1.y; a1.z += v1.z; a1.w += v1.w;
                    a2.x += v2.x; a2.y += v2.y; a2.z += v2.z; a2.w += v2.w;
                    a3.x += v3.x; a3.y += v3.y; a3.z += v3.z; a3.w += v3.w;
                }
                for (; e < e1; ++e){
                    int s0 = csr[e];
                    const float4 v0 = *(const float4*)&h[(size_t)s0*HD + lane*4];
                    a0.x += v0.x; a0.y += v0.y; a0.z += v0.z; a0.w += v0.w;
                }
            } else if (lane == 0) dgs[t] = 0.f;
            a0.x += a1.x; a0.y += a1.y; a0.z += a1.z; a0.w += a1.w;
            a2.x += a3.x; a2.y += a3.y; a2.z += a3.z; a2.w += a3.w;
            a4.x += a5.x; a4.y += a5.y; a4.z += a5.z; a4.w += a5.w;
            a6.x += a7.x; a6.y += a7.y; a6.z += a7.z; a6.w += a7.w;
            a0.x += a2.x; a0.y += a2.y; a0.z += a2.z; a0.w += a2.w;
            a4.x += a6.x; a4.y += a6.y; a4.z += a6.z; a4.w += a6.w;
            a0.x += a4.x; a0.y += a4.y; a0.z += a4.z; a0.w += a4.w;
            *(float4*)&lds[t][HD + lane*4] = a0;
        }
    }
    __syncthreads();

    const int cg = tid & 31, rg = tid >> 5;
    const int c0 = cg*4, r0 = rg*4;

    // conv = [h|aggr] @ Wf + deg*bc + ub
    const float4 bc4 = *(const float4*)&bcv[c0];
    const float4 ub4 = *(const float4*)&ub[c0];
    float acc[4][4];
    #pragma unroll
    for (int r = 0; r < 4; ++r){
        float d = dgs[r0+r];
        acc[r][0] = fmaf(d, bc4.x, ub4.x); acc[r][1] = fmaf(d, bc4.y, ub4.y);
        acc[r][2] = fmaf(d, bc4.z, ub4.z); acc[r][3] = fmaf(d, bc4.w, ub4.w);
    }
    #pragma unroll 4
    for (int k4 = 0; k4 < 64; ++k4){
        const float4 w0 = *(const float4*)&Wf[(size_t)(k4*4+0)*HD + c0];
        const float4 w1 = *(const float4*)&Wf[(size_t)(k4*4+1)*HD + c0];
        const float4 w2 = *(const float4*)&Wf[(size_t)(k4*4+2)*HD + c0];
        const float4 w3 = *(const float4*)&Wf[(size_t)(k4*4+3)*HD + c0];
        #pragma unroll
        for (int r = 0; r < 4; ++r){
            const float4 a = *(const float4*)&lds[r0+r][k4*4];
            acc[r][0]=fmaf(a.x,w0.x,fmaf(a.y,w1.x,fmaf(a.z,w2.x,fmaf(a.w,w3.x,acc[r][0]))));
            acc[r][1]=fmaf(a.x,w0.y,fmaf(a.y,w1.y,fmaf(a.z,w2.y,fmaf(a.w,w3.y,acc[r][1]))));
            acc[r][2]=fmaf(a.x,w0.z,fmaf(a.y,w1.z,fmaf(a.z,w2.z,fmaf(a.w,w3.z,acc[r][2]))));
            acc[r][3]=fmaf(a.x,w0.w,fmaf(a.y,w1.w,fmaf(a.z,w2.w,fmaf(a.w,w3.w,acc[r][3]))));
        }
    }
    __syncthreads();   // all conv-GEMM reads of the aggr half are done
    #pragma unroll
    for (int r = 0; r < 4; ++r)
        *(float4*)&lds[r0+r][HD + c0] = make_float4(acc[r][0],acc[r][1],acc[r][2],acc[r][3]);
    __syncthreads();

    // gate z = conv@gW_top + imp*gW[128] + gb   (conv now in lds cols 128..255)
    const float4 gwl = *(const float4*)&gW[(size_t)HD*HD + c0];
    const float4 gb4 = *(const float4*)&gb[c0];
    float z[4][4];
    #pragma unroll
    for (int r = 0; r < 4; ++r){
        float s = scs[r0+r];
        z[r][0] = fmaf(s, gwl.x, gb4.x); z[r][1] = fmaf(s, gwl.y, gb4.y);
        z[r][2] = fmaf(s, gwl.z, gb4.z); z[r][3] = fmaf(s, gwl.w, gb4.w);
    }
    #pragma unroll 4
    for (int k4 = 0; k4 < 32; ++k4){
        const float4 w0 = *(const float4*)&gW[(size_t)(k4*4+0)*HD + c0];
        const float4 w1 = *(const float4*)&gW[(size_t)(k4*4+1)*HD + c0];
        const float4 w2 = *(const float4*)&gW[(size_t)(k4*4+2)*HD + c0];
        const float4 w3 = *(const float4*)&gW[(size_t)(k4*4+3)*HD + c0];
        #pragma unroll
        for (int r = 0; r < 4; ++r){
            const float4 a = *(const float4*)&lds[r0+r][HD + k4*4];
            z[r][0]=fmaf(a.x,w0.x,fmaf(a.y,w1.x,fmaf(a.z,w2.x,fmaf(a.w,w3.x,z[r][0]))));
            z[r][1]=fmaf(a.x,w0.y,fmaf(a.y,w1.y,fmaf(a.z,w2.y,fmaf(a.w,w3.y,z[r][1]))));
            z[r][2]=fmaf(a.x,w0.z,fmaf(a.y,w1.z,fmaf(a.z,w2.z,fmaf(a.w,w3.z,z[r][2]))));
            z[r][3]=fmaf(a.x,w0.w,fmaf(a.y,w1.w,fmaf(a.z,w2.w,fmaf(a.w,w3.w,z[r][3]))));
        }
    }

    // epilogue: gate mix, store out, prop partials (conv still in acc regs)
    const float4 pr4 = *(const float4*)&prW[c0];
    float psum[4];
    #pragma unroll
    for (int r = 0; r < 4; ++r){
        const float4 hv = *(const float4*)&lds[r0+r][c0];
        float g0 = 1.f/(1.f + expf(-z[r][0]));
        float g1 = 1.f/(1.f + expf(-z[r][1]));
        float g2 = 1.f/(1.f + expf(-z[r][2]));
        float g3 = 1.f/(1.f + expf(-z[r][3]));
        float o0 = g0*acc[r][0] + (1.f-g0)*hv.x;
        float o1 = g1*acc[r][1] + (1.f-g1)*hv.y;
        float o2 = g2*acc[r][2] + (1.f-g2)*hv.z;
        float o3 = g3*acc[r][3] + (1.f-g3)*hv.w;
        if (base + r0 + r < NN)
            *(float4*)&outbuf[(size_t)(base+r0+r)*HD + c0] = make_float4(o0,o1,o2,o3);
        psum[r] = o0*pr4.x + o1*pr4.y + o2*pr4.z + o3*pr4.w;
    }
    #pragma unroll
    for (int r = 0; r < 4; ++r){
        float v = psum[r];
        #pragma unroll
        for (int off = 16; off > 0; off >>= 1) v += __shfl_xor(v, off);
        if (cg == 0) red[rg][r] = v;
    }
    __syncthreads();
    if (tid < MB && base + tid < NN)
        ta[base+tid] = 0.9f*scs[tid] + 0.1f*(red[tid>>2][tid&3] + prb[0]);
}

// ---------- CSR build (by dst) ----------
__global__ void k_deg(const int* __restrict__ dst, int* deg){
    int e = blockIdx.x*blockDim.x + threadIdx.x;
    if (e < NE) atomicAdd(&deg[dst[e]], 1);
}

// scan also writes the fill-cursor copy (saves a separate launch)
__global__ __launch_bounds__(1024) void k_scan(const int* __restrict__ deg,
                                               int* __restrict__ rowstart,
                                               int* __restrict__ cursor){
    __shared__ int wtot[16];
    __shared__ int woff[16];
    __shared__ int carry;
    int tid = threadIdx.x, lane = tid & 63, wv = tid >> 6;
    if (tid == 0) carry = 0;
    __syncthreads();
    for (int base = 0; base < NN; base += 1024){
        int i = base + tid;
        int v = (i < NN) ? deg[i] : 0;
        int x = v;
        #pragma unroll
        for (int off = 1; off < 64; off <<= 1){
            int y = __shfl_up(x, off);
            if (lane >= off) x += y;
        }
        if (lane == 63) wtot[wv] = x;
        __syncthreads();
        if (tid == 0){
            int a = carry;
            for (int w2 = 0; w2 < 16; ++w2){ woff[w2] = a; a += wtot[w2]; }
            carry = a;
        }
        __syncthreads();
        if (i < NN){
            int ex = woff[wv] + x - v;   // exclusive
            rowstart[i] = ex;
            cursor[i] = ex;
        }
    }
    __syncthreads();
    if (tid == 0) rowstart[NN] = carry;
}

__global__ void k_fill(const int* __restrict__ src, const int* __restrict__ dst,
                       int* cursor, int* __restrict__ csr){
    int e = blockIdx.x*blockDim.x + threadIdx.x;
    if (e < NE){
        int d = dst[e];
        int p = atomicAdd(&cursor[d], 1);
        csr[p] = src[e];
    }
}

// ---------- fused graph-norm (4 col-slices per graph) + importance chain ----
__global__ __launch_bounds__(256) void k_gnorm(
    const float* __restrict__ v, const int* __restrict__ gstart,
    const float* __restrict__ nw, const float* __restrict__ nb,
    const float* __restrict__ na, float* __restrict__ hout,
    const float* __restrict__ tsrc, float* __restrict__ tdst)
{
    int g = blockIdx.x;
    int part = blockIdx.y;
    int s = gstart[g], n = gstart[g+1] - s;
    int tid = threadIdx.x;

    if (part == 4){
        __shared__ float sv[1024];
        __shared__ float red[8];
        float lmn = 3.4e38f, lmx = -3.4e38f;
        for (int i = tid; i < n; i += 256){
            float val = tsrc[s+i]; sv[i] = val;
            lmn = fminf(lmn, val); lmx = fmaxf(lmx, val);
        }
        float lo, hi;
        block_minmax(lmn, lmx, red, lo, hi);
        float inv = 1.f/(hi - lo + 1e-8f);
        lmn = 3.4e38f; lmx = -3.4e38f;
        for (int i = tid; i < n; i += 256){
            float t2 = (sv[i] - lo)*inv;
            if (t2 < 0.1f) t2 = 0.f;
            sv[i] = t2;
            lmn = fminf(lmn, t2); lmx = fmaxf(lmx, t2);
        }
        float lo2, hi2;
        block_minmax(lmn, lmx, red, lo2, hi2);
        float inv2 = 1.f/(hi2 - lo2 + 1e-8f);
        for (int i = tid; i < n; i += 256) tdst[s+i] = (sv[i] - lo2)*inv2;
        return;
    }

    __shared__ float4 rs1[32][8];
    __shared__ float4 rs2[32][8];
    __shared__ float amv[32], scv[32], nbv[32];
    int rg = tid >> 3, c4l = tid & 7;
    size_t coff = (size_t)part*32 + c4l*4;
    float4 s1 = {0.f,0.f,0.f,0.f}, s2 = {0.f,0.f,0.f,0.f};
    for (int i = rg; i < n; i += 32){
        const float4 vv = *(const float4*)&v[(size_t)(s+i)*HD + coff];
        s1.x += vv.x; s1.y += vv.y; s1.z += vv.z; s1.w += vv.w;
        s2.x += vv.x*vv.x; s2.y += vv.y*vv.y; s2.z += vv.z*vv.z; s2.w += vv.w*vv.w;
    }
    rs1[rg][c4l] = s1; rs2[rg][c4l] = s2;
    __syncthreads();
    if (tid < 8){
        float4 t1 = {0.f,0.f,0.f,0.f}, t2 = {0.f,0.f,0.f,0.f};
        for (int r = 0; r < 32; ++r){
            float4 a = rs1[r][tid]; float4 b = rs2[r][tid];
            t1.x += a.x; t1.y += a.y; t1.z += a.z; t1.w += a.w;
            t2.x += b.x; t2.y += b.y; t2.z += b.z; t2.w += b.w;
        }
        float fn = (float)n;
        float S1[4] = {t1.x,t1.y,t1.z,t1.w};
        float S2[4] = {t2.x,t2.y,t2.z,t2.w};
        #pragma unroll
        for (int e = 0; e < 4; ++e){
            int j = part*32 + tid*4 + e;
            float m = S1[e]/fn;
            float aj = na[j];
            float var = S2[e]/fn - (2.f*aj - aj*aj)*m*m;
            float stdv = sqrtf(var + 1e-5f);
            amv[tid*4+e] = aj*m;
            scv[tid*4+e] = nw[j]/stdv;
            nbv[tid*4+e] = nb[j];
        }
    }
    __syncthreads();
    const float4 am4 = *(const float4*)&amv[c4l*4];
    const float4 sc4 = *(const float4*)&scv[c4l*4];
    const float4 nb4 = *(const float4*)&nbv[c4l*4];
    for (int i = rg; i < n; i += 32){
        const float4 vv = *(const float4*)&v[(size_t)(s+i)*HD + coff];
        float4 r;
        r.x = fmaxf((vv.x - am4.x)*sc4.x + nb4.x, 0.f);
        r.y = fmaxf((vv.y - am4.y)*sc4.y + nb4.y, 0.f);
        r.z = fmaxf((vv.z - am4.z)*sc4.z + nb4.z, 0.f);
        r.w = fmaxf((vv.w - am4.w)*sc4.w + nb4.w, 0.f);
        *(float4*)&hout[(size_t)(s+i)*HD + coff] = r;
    }
}

// ---------- fused final: column-sum + logits GEMM + final importance --------
__global__ __launch_bounds__(1024) void k_logits(
    const float* __restrict__ h, const int* __restrict__ gstart,
    const float* __restrict__ fW, const float* __restrict__ fb,
    const float* __restrict__ imp0, const float* __restrict__ impf,
    float* __restrict__ outp)
{
    __shared__ float4 rs1[32][32];
    __shared__ float gsum[HD];
    __shared__ float redn[32];
    int g = blockIdx.x;
    int s = gstart[g], n = gstart[g+1] - s;
    int tid = threadIdx.x;
    int c4 = tid & 31, rg = tid >> 5;
    float4 s1 = {0.f,0.f,0.f,0.f};
    for (int i = rg; i < n; i += 32){
        const float4 vv = *(const float4*)&h[(size_t)(s+i)*HD + c4*4];
        s1.x += vv.x; s1.y += vv.y; s1.z += vv.z; s1.w += vv.w;
    }
    rs1[rg][c4] = s1;
    __syncthreads();
    if (tid < 32){
        float4 t1 = {0.f,0.f,0.f,0.f};
        for (int r = 0; r < 32; ++r){
            float4 a = rs1[r][tid];
            t1.x += a.x; t1.y += a.y; t1.z += a.z; t1.w += a.w;
        }
        gsum[tid*4+0] = t1.x; gsum[tid*4+1] = t1.y;
        gsum[tid*4+2] = t1.z; gsum[tid*4+3] = t1.w;
    }
    __syncthreads();
    if (tid < 32){
        int o = tid;
        float acc = 0.f;
        for (int k = 0; k < HD; ++k) acc = fmaf(gsum[k], fW[k*32 + o], acc);
        outp[g*32 + o] = acc/(float)n + fb[o];
    }
    float val = 0.f;
    bool has = (tid < n);
    float lmn = 3.4e38f, lmx = -3.4e38f;
    if (has){ val = imp0[s+tid] + impf[s+tid]; lmn = val; lmx = val; }
    #pragma unroll
    for (int off = 32; off > 0; off >>= 1){
        lmn = fminf(lmn, __shfl_xor(lmn, off));
        lmx = fmaxf(lmx, __shfl_xor(lmx, off));
    }
    int wv = tid >> 6, lane = tid & 63;
    if (lane == 0){ redn[wv] = lmn; redn[16+wv] = lmx; }
    __syncthreads();
    float lo = redn[0], hi = redn[16];
    for (int r2 = 1; r2 < 16; ++r2){
        lo = fminf(lo, redn[r2]); hi = fmaxf(hi, redn[16+r2]);
    }
    if (has) outp[NG*32 + s + tid] = (val - lo)/(hi - lo + 1e-8f);
}

extern "C" void kernel_launch(void* const* d_in, const int* in_sizes, int n_in,
                              void* d_out, int out_size, void* d_ws, size_t ws_size,
                              hipStream_t stream){
    const float* x    = (const float*)d_in[0];
    const float* imp0 = (const float*)d_in[2];
    const float* pW   = (const float*)d_in[3];
    const float* pb   = (const float*)d_in[4];
    const float* iW   = (const float*)d_in[5];
    const float* ib   = (const float*)d_in[6];
    const float* msgW = (const float*)d_in[7];
    const float* msgb = (const float*)d_in[8];
    const float* updW = (const float*)d_in[9];
    const float* updb = (const float*)d_in[10];
    const float* gWt  = (const float*)d_in[11];
    const float* gb   = (const float*)d_in[12];
    const float* prW  = (const float*)d_in[13];
    const float* prb  = (const float*)d_in[14];
    const float* nw   = (const float*)d_in[15];
    const float* nb   = (const float*)d_in[16];
    const float* na   = (const float*)d_in[17];
    const float* fW   = (const float*)d_in[18];
    const float* fb   = (const float*)d_in[19];
    const int* eidx   = (const int*)d_in[20];
    const int* batch  = (const int*)d_in[21];
    const int* esrc = eidx;
    const int* edst = eidx + NE;
    float* outp = (float*)d_out;

    char* w = (char*)d_ws;
    size_t off = 0;
    auto alloc = [&](size_t bytes)->char*{
        char* p = w + off;
        off += (bytes + 255) & ~(size_t)255;
        return p;
    };
    float* h     = (float*)alloc((size_t)NN*HD*4);
    float* outA  = (float*)alloc((size_t)NN*HD*4);
    float* ta    = (float*)alloc((size_t)NN*4);
    float* imp   = (float*)alloc((size_t)NN*4);
    float* W0    = (float*)alloc((size_t)(FT+1)*HD*4);
    float* b0    = (float*)alloc((size_t)HD*4);
    float* Wf    = (float*)alloc((size_t)NLAYERS*2*HD*HD*4);
    float* bcv   = (float*)alloc((size_t)NLAYERS*HD*4);
    int* gstart  = (int*)alloc((size_t)(NG+1)*4);
    int* deg     = (int*)alloc((size_t)NN*4);
    int* rowst   = (int*)alloc((size_t)(NN+1)*4);
    int* cursor  = (int*)alloc((size_t)NN*4);
    int* csr     = (int*)alloc((size_t)NE*4);

    // graph boundaries
    k_gbounds<<<196, 256, 0, stream>>>(batch, gstart);

    // CSR by dst
    hipMemsetAsync(deg, 0, NN*4, stream);
    k_deg<<<3125, 256, 0, stream>>>(edst, deg);
    k_scan<<<1, 1024, 0, stream>>>(deg, rowst, cursor);
    k_fill<<<3125, 256, 0, stream>>>(esrc, edst, cursor, csr);

    // weight folds
    k_fold_init<<<1, 128, 0, stream>>>(pW, pb, iW, ib, W0, b0);
    k_fold_layer<<<dim3(257, NLAYERS), 128, 0, stream>>>(msgW, updW, msgb, Wf, bcv);

    // importance = normalize(imp0); h = init GEMM
    k_norm_graph<<<NG, 256, 0, stream>>>(imp0, gstart, imp);
    k_init<<<NBLK, 256, 0, stream>>>(x, imp, W0, b0, h);

    for (int l = 0; l < NLAYERS; ++l){
        k_layer<<<NBLK, 256, 0, stream>>>(
            h, rowst, csr, imp,
            Wf + (size_t)l*2*HD*HD, bcv + (size_t)l*HD,
            updb + (size_t)l*HD, gWt + (size_t)l*(HD+1)*HD, gb + (size_t)l*HD,
            prW + (size_t)l*HD, prb + l, outA, ta);
        k_gnorm<<<dim3(NG,5), 256, 0, stream>>>(outA, gstart,
            nw + (size_t)l*HD, nb + (size_t)l*HD, na + (size_t)l*HD, h, ta, imp);
    }

    // logits + final importance
    k_logits<<<NG, 1024, 0, stream>>>(h, gstart, fW, fb, imp0, imp, outp);
}

// Round 12
// 649.285 us; speedup vs baseline: 1.3709x; 1.0597x over previous
//
#include <hip/hip_runtime.h>
#include <cstdint>

#define NN 50000
#define NE 800000
#define NG 64
#define HD 128
#define FT 64
#define NLAYERS 3
#define MB 32
#define NBLK 1563   // ceil(NN/MB)
#define NCH 49      // ceil(NN/1024)

// ---------- graph boundaries (batch is sorted contiguous runs) ----------
__global__ void k_gbounds(const int* __restrict__ batch, int* __restrict__ gstart){
    int i = blockIdx.x*blockDim.x + threadIdx.x;
    if (i >= NN) return;
    int g = batch[i];
    if (i == 0){ for (int q = 0; q <= g; ++q) gstart[q] = 0; }
    else { int gp = batch[i-1]; for (int q = gp+1; q <= g; ++q) gstart[q] = i; }
    if (i == NN-1){ for (int q = g+1; q <= NG; ++q) gstart[q] = NN; }
}

// ---------- block-wide min/max reduce helper (256 threads = 4 waves) ----------
__device__ __forceinline__ void block_minmax(float lmn, float lmx, float* red,
                                             float& omn, float& omx){
    #pragma unroll
    for (int off = 32; off > 0; off >>= 1){
        lmn = fminf(lmn, __shfl_xor(lmn, off));
        lmx = fmaxf(lmx, __shfl_xor(lmx, off));
    }
    int wave = threadIdx.x >> 6;
    if ((threadIdx.x & 63) == 0){ red[wave] = lmn; red[4+wave] = lmx; }
    __syncthreads();
    omn = fminf(fminf(red[0], red[1]), fminf(red[2], red[3]));
    omx = fmaxf(fmaxf(red[4], red[5]), fmaxf(red[6], red[7]));
    __syncthreads();
}

// ---------- per-graph normalize (initial importance only) ----------
__global__ __launch_bounds__(256) void k_norm_graph(
    const float* __restrict__ va, const int* __restrict__ gstart,
    float* __restrict__ out)
{
    __shared__ float sv[1024];
    __shared__ float red[8];
    int g = blockIdx.x;
    int s = gstart[g], n = gstart[g+1] - s;
    int tid = threadIdx.x;
    float lmn = 3.4e38f, lmx = -3.4e38f;
    for (int i = tid; i < n; i += 256){
        float v = va[s+i];
        sv[i] = v;
        lmn = fminf(lmn, v); lmx = fmaxf(lmx, v);
    }
    float lo, hi;
    block_minmax(lmn, lmx, red, lo, hi);
    float inv = 1.f/(hi - lo + 1e-8f);
    for (int i = tid; i < n; i += 256) out[s+i] = (sv[i] - lo)*inv;
}

// Fold imp_proj into init_W: W0 is (FT+1) x HD, b0 = init_b + pb @ init_W[FT:]
__global__ void k_fold_init(const float* __restrict__ pW, const float* __restrict__ pb,
                            const float* __restrict__ iW, const float* __restrict__ ib,
                            float* __restrict__ W0, float* __restrict__ b0){
    int j = threadIdx.x;
    for (int k = 0; k < FT; ++k) W0[k*HD + j] = iW[k*HD + j];
    float w2 = 0.f, b2 = 0.f;
    for (int k = 0; k < HD; ++k){
        float w = iW[(FT + k)*HD + j];
        w2 += pW[k]*w;
        b2 += pb[k]*w;
    }
    W0[FT*HD + j] = w2;
    b0[j] = ib[j] + b2;
}

// Wf(256x128) = [uW_top ; msg_W @ uW_bot], bcv = msg_b @ uW_bot.
// grid (257, NLAYERS) x 128.
__global__ void k_fold_layer(const float* __restrict__ msgW, const float* __restrict__ updW,
                             const float* __restrict__ msgb,
                             float* __restrict__ WfA, float* __restrict__ bcvA){
    int l = blockIdx.y;
    const float* mW  = msgW + (size_t)l*HD*HD;
    const float* uW  = updW + (size_t)l*2*HD*HD;
    const float* mb  = msgb + (size_t)l*HD;
    float* Wf  = WfA  + (size_t)l*2*HD*HD;
    float* bcv = bcvA + (size_t)l*HD;
    int j = threadIdx.x;
    int r = blockIdx.x;
    if (r < HD){
        Wf[(size_t)r*HD + j] = uW[(size_t)r*HD + j];
    } else if (r < 2*HD){
        int rr = r - HD;
        const float* uWbot = uW + (size_t)HD*HD;
        float acc = 0.f;
        for (int k = 0; k < HD; ++k)
            acc = fmaf(mW[(size_t)rr*HD + k], uWbot[(size_t)k*HD + j], acc);
        Wf[(size_t)r*HD + j] = acc;
    } else {
        const float* uWbot = uW + (size_t)HD*HD;
        float acc = 0.f;
        for (int k = 0; k < HD; ++k)
            acc = fmaf(mb[k], uWbot[(size_t)k*HD + j], acc);
        bcv[j] = acc;
    }
}

// ---------- init GEMM: h = x @ W0[0:64] + imp*W0[64] + b0 ----------
__global__ __launch_bounds__(256) void k_init(
    const float* __restrict__ x, const float* __restrict__ imp,
    const float* __restrict__ W0, const float* __restrict__ b0v,
    float* __restrict__ h)
{
    __shared__ float lds[MB][FT];
    __shared__ float scs[MB];
    int base = blockIdx.x*MB, tid = threadIdx.x;
    #pragma unroll
    for (int i = 0; i < 2; ++i){
        int fidx = i*256 + tid;
        int t = fidx >> 4, c = fidx & 15;
        float4 v = {0.f,0.f,0.f,0.f};
        if (base + t < NN) v = *(const float4*)&x[(size_t)(base+t)*FT + c*4];
        *(float4*)&lds[t][c*4] = v;
    }
    if (tid < MB) scs[tid] = (base+tid < NN) ? imp[base+tid] : 0.f;
    __syncthreads();

    const int cg = tid & 31, rg = tid >> 5;
    const int c0 = cg*4, r0 = rg*4;
    const float4 wl4 = *(const float4*)&W0[(size_t)FT*HD + c0];
    const float4 b4  = *(const float4*)&b0v[c0];
    float acc[4][4];
    #pragma unroll
    for (int r = 0; r < 4; ++r){
        float s = scs[r0+r];
        acc[r][0] = fmaf(s, wl4.x, b4.x); acc[r][1] = fmaf(s, wl4.y, b4.y);
        acc[r][2] = fmaf(s, wl4.z, b4.z); acc[r][3] = fmaf(s, wl4.w, b4.w);
    }
    #pragma unroll 4
    for (int k4 = 0; k4 < 16; ++k4){
        const float4 w0 = *(const float4*)&W0[(size_t)(k4*4+0)*HD + c0];
        const float4 w1 = *(const float4*)&W0[(size_t)(k4*4+1)*HD + c0];
        const float4 w2 = *(const float4*)&W0[(size_t)(k4*4+2)*HD + c0];
        const float4 w3 = *(const float4*)&W0[(size_t)(k4*4+3)*HD + c0];
        #pragma unroll
        for (int r = 0; r < 4; ++r){
            const float4 a = *(const float4*)&lds[r0+r][k4*4];
            acc[r][0]=fmaf(a.x,w0.x,fmaf(a.y,w1.x,fmaf(a.z,w2.x,fmaf(a.w,w3.x,acc[r][0]))));
            acc[r][1]=fmaf(a.x,w0.y,fmaf(a.y,w1.y,fmaf(a.z,w2.y,fmaf(a.w,w3.y,acc[r][1]))));
            acc[r][2]=fmaf(a.x,w0.z,fmaf(a.y,w1.z,fmaf(a.z,w2.z,fmaf(a.w,w3.z,acc[r][2]))));
            acc[r][3]=fmaf(a.x,w0.w,fmaf(a.y,w1.w,fmaf(a.z,w2.w,fmaf(a.w,w3.w,acc[r][3]))));
        }
    }
    #pragma unroll
    for (int r = 0; r < 4; ++r)
        if (base + r0 + r < NN)
            *(float4*)&h[(size_t)(base+r0+r)*HD + c0] =
                make_float4(acc[r][0], acc[r][1], acc[r][2], acc[r][3]);
}

// ---------- per-layer mega kernel: fused gather + conv + gate ----------
__global__ __launch_bounds__(256, 4) void k_layer(
    const float* __restrict__ h,
    const int* __restrict__ rowst, const int* __restrict__ csr,
    const float* __restrict__ imp,
    const float* __restrict__ Wf, const float* __restrict__ bcv,
    const float* __restrict__ ub,
    const float* __restrict__ gW, const float* __restrict__ gb,
    const float* __restrict__ prW, const float* __restrict__ prb,
    float* __restrict__ outbuf, float* __restrict__ ta)
{
    __shared__ float lds[MB][256];   // cols 0..127: h ; 128..255: aggr, then conv
    __shared__ float scs[MB];
    __shared__ float dgs[MB];
    __shared__ float red[8][4];
    const int base = blockIdx.x*MB, tid = threadIdx.x;

    // stage h tile (cols 0..127): 1024 float4, 4 per thread
    #pragma unroll
    for (int i = 0; i < 4; ++i){
        int fidx = i*256 + tid;
        int t = fidx >> 5, c = fidx & 31;
        float4 v = {0.f,0.f,0.f,0.f};
        if (base + t < NN) v = *(const float4*)&h[(size_t)(base+t)*HD + c*4];
        *(float4*)&lds[t][c*4] = v;
    }
    if (tid < MB) scs[tid] = (base+tid < NN) ? imp[base+tid] : 0.f;

    // fused gather into cols 128..255: 4 passes x 8 nodes, 32 lanes/node
    {
        const int lane = tid & 31;
        #pragma unroll
        for (int pass = 0; pass < 4; ++pass){
            const int t = pass*8 + (tid >> 5);
            const int node = base + t;
            float4 a0 = {0.f,0.f,0.f,0.f}, a1 = a0, a2 = a0, a3 = a0;
            float4 a4 = a0, a5 = a0, a6 = a0, a7 = a0;
            if (node < NN){
                int e0 = rowst[node], e1 = rowst[node+1];
                if (lane == 0) dgs[t] = (float)(e1 - e0);
                int e = e0;
                for (; e + 7 < e1; e += 8){
                    int s0 = csr[e],   s1 = csr[e+1], s2 = csr[e+2], s3 = csr[e+3];
                    int s4 = csr[e+4], s5 = csr[e+5], s6 = csr[e+6], s7 = csr[e+7];
                    const float4 v0 = *(const float4*)&h[(size_t)s0*HD + lane*4];
                    const float4 v1 = *(const float4*)&h[(size_t)s1*HD + lane*4];
                    const float4 v2 = *(const float4*)&h[(size_t)s2*HD + lane*4];
                    const float4 v3 = *(const float4*)&h[(size_t)s3*HD + lane*4];
                    const float4 v4 = *(const float4*)&h[(size_t)s4*HD + lane*4];
                    const float4 v5 = *(const float4*)&h[(size_t)s5*HD + lane*4];
                    const float4 v6 = *(const float4*)&h[(size_t)s6*HD + lane*4];
                    const float4 v7 = *(const float4*)&h[(size_t)s7*HD + lane*4];
                    a0.x += v0.x; a0.y += v0.y; a0.z += v0.z; a0.w += v0.w;
                    a1.x += v1.x; a1.y += v1.y; a1.z += v1.z; a1.w += v1.w;
                    a2.x += v2.x; a2.y += v2.y; a2.z += v2.z; a2.w += v2.w;
                    a3.x += v3.x; a3.y += v3.y; a3.z += v3.z; a3.w += v3.w;
                    a4.x += v4.x; a4.y += v4.y; a4.z += v4.z; a4.w += v4.w;
                    a5.x += v5.x; a5.y += v5.y; a5.z += v5.z; a5.w += v5.w;
                    a6.x += v6.x; a6.y += v6.y; a6.z += v6.z; a6.w += v6.w;
                    a7.x += v7.x; a7.y += v7.y; a7.z += v7.z; a7.w += v7.w;
                }
                for (; e + 3 < e1; e += 4){
                    int s0 = csr[e], s1 = csr[e+1], s2 = csr[e+2], s3 = csr[e+3];
                    const float4 v0 = *(const float4*)&h[(size_t)s0*HD + lane*4];
                    const float4 v1 = *(const float4*)&h[(size_t)s1*HD + lane*4];
                    const float4 v2 = *(const float4*)&h[(size_t)s2*HD + lane*4];
                    const float4 v3 = *(const float4*)&h[(size_t)s3*HD + lane*4];
                    a0.x += v0.x; a0.y += v0.y; a0.z += v0.z; a0.w += v0.w;
                    a1.x += v1.x; a1.y += v1.y; a1.z += v1.z; a1.w += v1.w;
                    a2.x += v2.x; a2.y += v2.y; a2.z += v2.z; a2.w += v2.w;
                    a3.x += v3.x; a3.y += v3.y; a3.z += v3.z; a3.w += v3.w;
                }
                for (; e < e1; ++e){
                    int s0 = csr[e];
                    const float4 v0 = *(const float4*)&h[(size_t)s0*HD + lane*4];
                    a0.x += v0.x; a0.y += v0.y; a0.z += v0.z; a0.w += v0.w;
                }
            } else if (lane == 0) dgs[t] = 0.f;
            a0.x += a1.x; a0.y += a1.y; a0.z += a1.z; a0.w += a1.w;
            a2.x += a3.x; a2.y += a3.y; a2.z += a3.z; a2.w += a3.w;
            a4.x += a5.x; a4.y += a5.y; a4.z += a5.z; a4.w += a5.w;
            a6.x += a7.x; a6.y += a7.y; a6.z += a7.z; a6.w += a7.w;
            a0.x += a2.x; a0.y += a2.y; a0.z += a2.z; a0.w += a2.w;
            a4.x += a6.x; a4.y += a6.y; a4.z += a6.z; a4.w += a6.w;
            a0.x += a4.x; a0.y += a4.y; a0.z += a4.z; a0.w += a4.w;
            *(float4*)&lds[t][HD + lane*4] = a0;
        }
    }
    __syncthreads();

    const int cg = tid & 31, rg = tid >> 5;
    const int c0 = cg*4, r0 = rg*4;

    // conv = [h|aggr] @ Wf + deg*bc + ub
    const float4 bc4 = *(const float4*)&bcv[c0];
    const float4 ub4 = *(const float4*)&ub[c0];
    float acc[4][4];
    #pragma unroll
    for (int r = 0; r < 4; ++r){
        float d = dgs[r0+r];
        acc[r][0] = fmaf(d, bc4.x, ub4.x); acc[r][1] = fmaf(d, bc4.y, ub4.y);
        acc[r][2] = fmaf(d, bc4.z, ub4.z); acc[r][3] = fmaf(d, bc4.w, ub4.w);
    }
    #pragma unroll 4
    for (int k4 = 0; k4 < 64; ++k4){
        const float4 w0 = *(const float4*)&Wf[(size_t)(k4*4+0)*HD + c0];
        const float4 w1 = *(const float4*)&Wf[(size_t)(k4*4+1)*HD + c0];
        const float4 w2 = *(const float4*)&Wf[(size_t)(k4*4+2)*HD + c0];
        const float4 w3 = *(const float4*)&Wf[(size_t)(k4*4+3)*HD + c0];
        #pragma unroll
        for (int r = 0; r < 4; ++r){
            const float4 a = *(const float4*)&lds[r0+r][k4*4];
            acc[r][0]=fmaf(a.x,w0.x,fmaf(a.y,w1.x,fmaf(a.z,w2.x,fmaf(a.w,w3.x,acc[r][0]))));
            acc[r][1]=fmaf(a.x,w0.y,fmaf(a.y,w1.y,fmaf(a.z,w2.y,fmaf(a.w,w3.y,acc[r][1]))));
            acc[r][2]=fmaf(a.x,w0.z,fmaf(a.y,w1.z,fmaf(a.z,w2.z,fmaf(a.w,w3.z,acc[r][2]))));
            acc[r][3]=fmaf(a.x,w0.w,fmaf(a.y,w1.w,fmaf(a.z,w2.w,fmaf(a.w,w3.w,acc[r][3]))));
        }
    }
    __syncthreads();   // all conv-GEMM reads of the aggr half are done
    #pragma unroll
    for (int r = 0; r < 4; ++r)
        *(float4*)&lds[r0+r][HD + c0] = make_float4(acc[r][0],acc[r][1],acc[r][2],acc[r][3]);
    __syncthreads();

    // gate z = conv@gW_top + imp*gW[128] + gb   (conv now in lds cols 128..255)
    const float4 gwl = *(const float4*)&gW[(size_t)HD*HD + c0];
    const float4 gb4 = *(const float4*)&gb[c0];
    float z[4][4];
    #pragma unroll
    for (int r = 0; r < 4; ++r){
        float s = scs[r0+r];
        z[r][0] = fmaf(s, gwl.x, gb4.x); z[r][1] = fmaf(s, gwl.y, gb4.y);
        z[r][2] = fmaf(s, gwl.z, gb4.z); z[r][3] = fmaf(s, gwl.w, gb4.w);
    }
    #pragma unroll 4
    for (int k4 = 0; k4 < 32; ++k4){
        const float4 w0 = *(const float4*)&gW[(size_t)(k4*4+0)*HD + c0];
        const float4 w1 = *(const float4*)&gW[(size_t)(k4*4+1)*HD + c0];
        const float4 w2 = *(const float4*)&gW[(size_t)(k4*4+2)*HD + c0];
        const float4 w3 = *(const float4*)&gW[(size_t)(k4*4+3)*HD + c0];
        #pragma unroll
        for (int r = 0; r < 4; ++r){
            const float4 a = *(const float4*)&lds[r0+r][HD + k4*4];
            z[r][0]=fmaf(a.x,w0.x,fmaf(a.y,w1.x,fmaf(a.z,w2.x,fmaf(a.w,w3.x,z[r][0]))));
            z[r][1]=fmaf(a.x,w0.y,fmaf(a.y,w1.y,fmaf(a.z,w2.y,fmaf(a.w,w3.y,z[r][1]))));
            z[r][2]=fmaf(a.x,w0.z,fmaf(a.y,w1.z,fmaf(a.z,w2.z,fmaf(a.w,w3.z,z[r][2]))));
            z[r][3]=fmaf(a.x,w0.w,fmaf(a.y,w1.w,fmaf(a.z,w2.w,fmaf(a.w,w3.w,z[r][3]))));
        }
    }

    // epilogue: gate mix, store out, prop partials (conv still in acc regs)
    const float4 pr4 = *(const float4*)&prW[c0];
    float psum[4];
    #pragma unroll
    for (int r = 0; r < 4; ++r){
        const float4 hv = *(const float4*)&lds[r0+r][c0];
        float g0 = 1.f/(1.f + expf(-z[r][0]));
        float g1 = 1.f/(1.f + expf(-z[r][1]));
        float g2 = 1.f/(1.f + expf(-z[r][2]));
        float g3 = 1.f/(1.f + expf(-z[r][3]));
        float o0 = g0*acc[r][0] + (1.f-g0)*hv.x;
        float o1 = g1*acc[r][1] + (1.f-g1)*hv.y;
        float o2 = g2*acc[r][2] + (1.f-g2)*hv.z;
        float o3 = g3*acc[r][3] + (1.f-g3)*hv.w;
        if (base + r0 + r < NN)
            *(float4*)&outbuf[(size_t)(base+r0+r)*HD + c0] = make_float4(o0,o1,o2,o3);
        psum[r] = o0*pr4.x + o1*pr4.y + o2*pr4.z + o3*pr4.w;
    }
    #pragma unroll
    for (int r = 0; r < 4; ++r){
        float v = psum[r];
        #pragma unroll
        for (int off = 16; off > 0; off >>= 1) v += __shfl_xor(v, off);
        if (cg == 0) red[rg][r] = v;
    }
    __syncthreads();
    if (tid < MB && base + tid < NN)
        ta[base+tid] = 0.9f*scs[tid] + 0.1f*(red[tid>>2][tid&3] + prb[0]);
}

// ---------- CSR build (by dst) ----------
__global__ void k_deg(const int* __restrict__ dst, int* deg){
    int e = blockIdx.x*blockDim.x + threadIdx.x;
    if (e < NE) atomicAdd(&deg[dst[e]], 1);
}

// parallel 3-phase scan: per-chunk sums -> scan of sums -> per-chunk rescan
__global__ __launch_bounds__(1024) void k_scan1(const int* __restrict__ deg,
                                                int* __restrict__ bsum){
    __shared__ int wred[16];
    int b = blockIdx.x, tid = threadIdx.x;
    int i = b*1024 + tid;
    int v = (i < NN) ? deg[i] : 0;
    #pragma unroll
    for (int off = 32; off > 0; off >>= 1) v += __shfl_xor(v, off);
    if ((tid & 63) == 0) wred[tid >> 6] = v;
    __syncthreads();
    if (tid < 16){
        int s = wred[tid];
        #pragma unroll
        for (int off = 8; off > 0; off >>= 1) s += __shfl_xor(s, off);
        if (tid == 0) bsum[b] = s;
    }
}

__global__ void k_scan2(const int* __restrict__ bsum, int* __restrict__ boff){
    int tid = threadIdx.x;   // 64 threads, NCH=49 values
    int v = (tid < NCH) ? bsum[tid] : 0;
    int x = v;
    #pragma unroll
    for (int off = 1; off < 64; off <<= 1){
        int y = __shfl_up(x, off);
        if (tid >= off) x += y;
    }
    if (tid < NCH) boff[tid] = x - v;   // exclusive
}

__global__ __launch_bounds__(1024) void k_scan3(const int* __restrict__ deg,
                                                const int* __restrict__ boff,
                                                int* __restrict__ rowstart,
                                                int* __restrict__ cursor){
    __shared__ int wtot[16];
    __shared__ int woff[16];
    int b = blockIdx.x, tid = threadIdx.x, lane = tid & 63, wv = tid >> 6;
    int i = b*1024 + tid;
    int v = (i < NN) ? deg[i] : 0;
    int x = v;
    #pragma unroll
    for (int off = 1; off < 64; off <<= 1){
        int y = __shfl_up(x, off);
        if (lane >= off) x += y;
    }
    if (lane == 63) wtot[wv] = x;
    __syncthreads();
    if (tid == 0){
        int a = boff[b];
        for (int w2 = 0; w2 < 16; ++w2){ woff[w2] = a; a += wtot[w2]; }
    }
    __syncthreads();
    if (i < NN){
        int ex = woff[wv] + x - v;   // exclusive
        rowstart[i] = ex;
        cursor[i] = ex;
    }
    if (b == 0 && tid == 0) rowstart[NN] = NE;
}

__global__ void k_fill(const int* __restrict__ src, const int* __restrict__ dst,
                       int* cursor, int* __restrict__ csr){
    int e = blockIdx.x*blockDim.x + threadIdx.x;
    if (e < NE){
        int d = dst[e];
        int p = atomicAdd(&cursor[d], 1);
        csr[p] = src[e];
    }
}

// ---------- fused graph-norm (4 col-slices per graph) + importance chain ----
__global__ __launch_bounds__(256) void k_gnorm(
    const float* __restrict__ v, const int* __restrict__ gstart,
    const float* __restrict__ nw, const float* __restrict__ nb,
    const float* __restrict__ na, float* __restrict__ hout,
    const float* __restrict__ tsrc, float* __restrict__ tdst)
{
    int g = blockIdx.x;
    int part = blockIdx.y;
    int s = gstart[g], n = gstart[g+1] - s;
    int tid = threadIdx.x;

    if (part == 4){
        __shared__ float sv[1024];
        __shared__ float red[8];
        float lmn = 3.4e38f, lmx = -3.4e38f;
        for (int i = tid; i < n; i += 256){
            float val = tsrc[s+i]; sv[i] = val;
            lmn = fminf(lmn, val); lmx = fmaxf(lmx, val);
        }
        float lo, hi;
        block_minmax(lmn, lmx, red, lo, hi);
        float inv = 1.f/(hi - lo + 1e-8f);
        lmn = 3.4e38f; lmx = -3.4e38f;
        for (int i = tid; i < n; i += 256){
            float t2 = (sv[i] - lo)*inv;
            if (t2 < 0.1f) t2 = 0.f;
            sv[i] = t2;
            lmn = fminf(lmn, t2); lmx = fmaxf(lmx, t2);
        }
        float lo2, hi2;
        block_minmax(lmn, lmx, red, lo2, hi2);
        float inv2 = 1.f/(hi2 - lo2 + 1e-8f);
        for (int i = tid; i < n; i += 256) tdst[s+i] = (sv[i] - lo2)*inv2;
        return;
    }

    __shared__ float4 rs1[32][8];
    __shared__ float4 rs2[32][8];
    __shared__ float amv[32], scv[32], nbv[32];
    int rg = tid >> 3, c4l = tid & 7;
    size_t coff = (size_t)part*32 + c4l*4;
    float4 s1 = {0.f,0.f,0.f,0.f}, s2 = {0.f,0.f,0.f,0.f};
    for (int i = rg; i < n; i += 32){
        const float4 vv = *(const float4*)&v[(size_t)(s+i)*HD + coff];
        s1.x += vv.x; s1.y += vv.y; s1.z += vv.z; s1.w += vv.w;
        s2.x += vv.x*vv.x; s2.y += vv.y*vv.y; s2.z += vv.z*vv.z; s2.w += vv.w*vv.w;
    }
    rs1[rg][c4l] = s1; rs2[rg][c4l] = s2;
    __syncthreads();
    if (tid < 8){
        float4 t1 = {0.f,0.f,0.f,0.f}, t2 = {0.f,0.f,0.f,0.f};
        for (int r = 0; r < 32; ++r){
            float4 a = rs1[r][tid]; float4 b = rs2[r][tid];
            t1.x += a.x; t1.y += a.y; t1.z += a.z; t1.w += a.w;
            t2.x += b.x; t2.y += b.y; t2.z += b.z; t2.w += b.w;
        }
        float fn = (float)n;
        float S1[4] = {t1.x,t1.y,t1.z,t1.w};
        float S2[4] = {t2.x,t2.y,t2.z,t2.w};
        #pragma unroll
        for (int e = 0; e < 4; ++e){
            int j = part*32 + tid*4 + e;
            float m = S1[e]/fn;
            float aj = na[j];
            float var = S2[e]/fn - (2.f*aj - aj*aj)*m*m;
            float stdv = sqrtf(var + 1e-5f);
            amv[tid*4+e] = aj*m;
            scv[tid*4+e] = nw[j]/stdv;
            nbv[tid*4+e] = nb[j];
        }
    }
    __syncthreads();
    const float4 am4 = *(const float4*)&amv[c4l*4];
    const float4 sc4 = *(const float4*)&scv[c4l*4];
    const float4 nb4 = *(const float4*)&nbv[c4l*4];
    for (int i = rg; i < n; i += 32){
        const float4 vv = *(const float4*)&v[(size_t)(s+i)*HD + coff];
        float4 r;
        r.x = fmaxf((vv.x - am4.x)*sc4.x + nb4.x, 0.f);
        r.y = fmaxf((vv.y - am4.y)*sc4.y + nb4.y, 0.f);
        r.z = fmaxf((vv.z - am4.z)*sc4.z + nb4.z, 0.f);
        r.w = fmaxf((vv.w - am4.w)*sc4.w + nb4.w, 0.f);
        *(float4*)&hout[(size_t)(s+i)*HD + coff] = r;
    }
}

// ---------- fused final: column-sum + logits GEMM + final importance --------
__global__ __launch_bounds__(1024) void k_logits(
    const float* __restrict__ h, const int* __restrict__ gstart,
    const float* __restrict__ fW, const float* __restrict__ fb,
    const float* __restrict__ imp0, const float* __restrict__ impf,
    float* __restrict__ outp)
{
    __shared__ float4 rs1[32][32];
    __shared__ float gsum[HD];
    __shared__ float redn[32];
    int g = blockIdx.x;
    int s = gstart[g], n = gstart[g+1] - s;
    int tid = threadIdx.x;
    int c4 = tid & 31, rg = tid >> 5;
    float4 s1 = {0.f,0.f,0.f,0.f};
    for (int i = rg; i < n; i += 32){
        const float4 vv = *(const float4*)&h[(size_t)(s+i)*HD + c4*4];
        s1.x += vv.x; s1.y += vv.y; s1.z += vv.z; s1.w += vv.w;
    }
    rs1[rg][c4] = s1;
    __syncthreads();
    if (tid < 32){
        float4 t1 = {0.f,0.f,0.f,0.f};
        for (int r = 0; r < 32; ++r){
            float4 a = rs1[r][tid];
            t1.x += a.x; t1.y += a.y; t1.z += a.z; t1.w += a.w;
        }
        gsum[tid*4+0] = t1.x; gsum[tid*4+1] = t1.y;
        gsum[tid*4+2] = t1.z; gsum[tid*4+3] = t1.w;
    }
    __syncthreads();
    if (tid < 32){
        int o = tid;
        float acc = 0.f;
        for (int k = 0; k < HD; ++k) acc = fmaf(gsum[k], fW[k*32 + o], acc);
        outp[g*32 + o] = acc/(float)n + fb[o];
    }
    float val = 0.f;
    bool has = (tid < n);
    float lmn = 3.4e38f, lmx = -3.4e38f;
    if (has){ val = imp0[s+tid] + impf[s+tid]; lmn = val; lmx = val; }
    #pragma unroll
    for (int off = 32; off > 0; off >>= 1){
        lmn = fminf(lmn, __shfl_xor(lmn, off));
        lmx = fmaxf(lmx, __shfl_xor(lmx, off));
    }
    int wv = tid >> 6, lane = tid & 63;
    if (lane == 0){ redn[wv] = lmn; redn[16+wv] = lmx; }
    __syncthreads();
    float lo = redn[0], hi = redn[16];
    for (int r2 = 1; r2 < 16; ++r2){
        lo = fminf(lo, redn[r2]); hi = fmaxf(hi, redn[16+r2]);
    }
    if (has) outp[NG*32 + s + tid] = (val - lo)/(hi - lo + 1e-8f);
}

extern "C" void kernel_launch(void* const* d_in, const int* in_sizes, int n_in,
                              void* d_out, int out_size, void* d_ws, size_t ws_size,
                              hipStream_t stream){
    const float* x    = (const float*)d_in[0];
    const float* imp0 = (const float*)d_in[2];
    const float* pW   = (const float*)d_in[3];
    const float* pb   = (const float*)d_in[4];
    const float* iW   = (const float*)d_in[5];
    const float* ib   = (const float*)d_in[6];
    const float* msgW = (const float*)d_in[7];
    const float* msgb = (const float*)d_in[8];
    const float* updW = (const float*)d_in[9];
    const float* updb = (const float*)d_in[10];
    const float* gWt  = (const float*)d_in[11];
    const float* gb   = (const float*)d_in[12];
    const float* prW  = (const float*)d_in[13];
    const float* prb  = (const float*)d_in[14];
    const float* nw   = (const float*)d_in[15];
    const float* nb   = (const float*)d_in[16];
    const float* na   = (const float*)d_in[17];
    const float* fW   = (const float*)d_in[18];
    const float* fb   = (const float*)d_in[19];
    const int* eidx   = (const int*)d_in[20];
    const int* batch  = (const int*)d_in[21];
    const int* esrc = eidx;
    const int* edst = eidx + NE;
    float* outp = (float*)d_out;

    char* w = (char*)d_ws;
    size_t off = 0;
    auto alloc = [&](size_t bytes)->char*{
        char* p = w + off;
        off += (bytes + 255) & ~(size_t)255;
        return p;
    };
    float* h     = (float*)alloc((size_t)NN*HD*4);
    float* outA  = (float*)alloc((size_t)NN*HD*4);
    float* ta    = (float*)alloc((size_t)NN*4);
    float* imp   = (float*)alloc((size_t)NN*4);
    float* W0    = (float*)alloc((size_t)(FT+1)*HD*4);
    float* b0    = (float*)alloc((size_t)HD*4);
    float* Wf    = (float*)alloc((size_t)NLAYERS*2*HD*HD*4);
    float* bcv   = (float*)alloc((size_t)NLAYERS*HD*4);
    int* gstart  = (int*)alloc((size_t)(NG+1)*4);
    int* deg     = (int*)alloc((size_t)NN*4);
    int* rowst   = (int*)alloc((size_t)(NN+1)*4);
    int* cursor  = (int*)alloc((size_t)NN*4);
    int* csr     = (int*)alloc((size_t)NE*4);
    int* bsum    = (int*)alloc((size_t)NCH*4);
    int* boff    = (int*)alloc((size_t)NCH*4);

    // graph boundaries
    k_gbounds<<<196, 256, 0, stream>>>(batch, gstart);

    // CSR by dst (parallel 3-phase scan)
    hipMemsetAsync(deg, 0, NN*4, stream);
    k_deg<<<3125, 256, 0, stream>>>(edst, deg);
    k_scan1<<<NCH, 1024, 0, stream>>>(deg, bsum);
    k_scan2<<<1, 64, 0, stream>>>(bsum, boff);
    k_scan3<<<NCH, 1024, 0, stream>>>(deg, boff, rowst, cursor);
    k_fill<<<3125, 256, 0, stream>>>(esrc, edst, cursor, csr);

    // weight folds
    k_fold_init<<<1, 128, 0, stream>>>(pW, pb, iW, ib, W0, b0);
    k_fold_layer<<<dim3(257, NLAYERS), 128, 0, stream>>>(msgW, updW, msgb, Wf, bcv);

    // importance = normalize(imp0); h = init GEMM
    k_norm_graph<<<NG, 256, 0, stream>>>(imp0, gstart, imp);
    k_init<<<NBLK, 256, 0, stream>>>(x, imp, W0, b0, h);

    for (int l = 0; l < NLAYERS; ++l){
        k_layer<<<NBLK, 256, 0, stream>>>(
            h, rowst, csr, imp,
            Wf + (size_t)l*2*HD*HD, bcv + (size_t)l*HD,
            updb + (size_t)l*HD, gWt + (size_t)l*(HD+1)*HD, gb + (size_t)l*HD,
            prW + (size_t)l*HD, prb + l, outA, ta);
        k_gnorm<<<dim3(NG,5), 256, 0, stream>>>(outA, gstart,
            nw + (size_t)l*HD, nb + (size_t)l*HD, na + (size_t)l*HD, h, ta, imp);
    }

    // logits + final importance
    k_logits<<<NG, 1024, 0, stream>>>(h, gstart, fW, fb, imp0, imp, outp);
}